// Round 12
// baseline (374.459 us; speedup 1.0000x reference)
//
#include <hip/hip_runtime.h>
#include <math.h>

#define NB    200
#define DIMH  128
#define ROWS  4
#define TPB   256
#define NITER 12   // tau err 0.411*2^-12 ~ 1e-4 -> p err ~1e-3, threshold 8.5e-2
#define NJT   13   // j-tiles of 16 covering 208
#define KJ2   112  // padded j-pairs for PV (224 j's)

typedef __attribute__((ext_vector_type(8))) short  short8v;  // 8 bf16 (MFMA A/B frag)
typedef __attribute__((ext_vector_type(4))) float  f32x4;    // MFMA C/D frag
typedef __attribute__((ext_vector_type(4))) unsigned u32x4;

#define WF_U32 32768   // W-frag table: 8nt*8ks*64lane*4 u32 (hi) + same (lo)

// Truncation hi/lo split: hi = top-16-bits of f32 (exact), lo = x - hi (exact f32).
__device__ __forceinline__ unsigned pack_hi2(float a, float b){
    return (__builtin_bit_cast(unsigned, a) >> 16) |
           (__builtin_bit_cast(unsigned, b) & 0xFFFF0000u);
}
__device__ __forceinline__ float hi_of(float x){
    return __builtin_bit_cast(float, __builtin_bit_cast(unsigned, x) & 0xFFFF0000u);
}
__device__ __forceinline__ float rdlane(float v, int l){
    return __builtin_bit_cast(float,
        __builtin_amdgcn_readlane(__builtin_bit_cast(int, v), l));
}
__device__ __forceinline__ float wsum_dpp(float v){
#define DPP_ADD(ctrl, rmask)                                                     \
    {                                                                            \
        int t_ = __builtin_amdgcn_update_dpp(0, __builtin_bit_cast(int, v),      \
                                             ctrl, rmask, 0xf, false);           \
        v += __builtin_bit_cast(float, t_);                                      \
    }
    DPP_ADD(0x111, 0xf)
    DPP_ADD(0x112, 0xf)
    DPP_ADD(0x114, 0xf)
    DPP_ADD(0x118, 0xf)
    DPP_ADD(0x142, 0xa)
    DPP_ADD(0x143, 0xc)
#undef DPP_ADD
    return rdlane(v, 63);
}
__device__ __forceinline__ float wmax_dpp(float v){
#define DPP_MAX(ctrl, rmask)                                                     \
    {                                                                            \
        int t_ = __builtin_amdgcn_update_dpp(__builtin_bit_cast(int, v),         \
                                             __builtin_bit_cast(int, v),         \
                                             ctrl, rmask, 0xf, false);           \
        v = fmaxf(v, __builtin_bit_cast(float, t_));                             \
    }
    DPP_MAX(0x111, 0xf)
    DPP_MAX(0x112, 0xf)
    DPP_MAX(0x114, 0xf)
    DPP_MAX(0x118, 0xf)
    DPP_MAX(0x142, 0xa)
    DPP_MAX(0x143, 0xc)
#undef DPP_MAX
    return rdlane(v, 63);
}

// One-time W -> bf16 hi/lo fragment table (gate MFMA B layout). Validated r10.
__global__ __launch_bounds__(64) void conv_w(const float* __restrict__ W,
                                             unsigned* __restrict__ wf){
    const int lane = threadIdx.x;
    const int ks = blockIdx.x & 7, nt = blockIdx.x >> 3;
    const int krow = ks * 32 + (lane >> 4) * 8;
    const int col  = nt * 16 + (lane & 15);
    unsigned hi[4], lo[4];
    #pragma unroll
    for (int q2 = 0; q2 < 4; ++q2) {
        float v0 = W[(size_t)(krow + 2 * q2) * DIMH + col];
        float v1 = W[(size_t)(krow + 2 * q2 + 1) * DIMH + col];
        hi[q2] = pack_hi2(v0, v1);
        lo[q2] = pack_hi2(v0 - hi_of(v0), v1 - hi_of(v1));
    }
    const unsigned base = (blockIdx.x * 64 + lane) * 4;
    *(u32x4*)&wf[base]              = (u32x4){hi[0], hi[1], hi[2], hi[3]};
    *(u32x4*)&wf[WF_U32 / 2 + base] = (u32x4){lo[0], lo[1], lo[2], lo[3]};
}

// hidden -> hs[b][j][d2] bf16 hi/lo (row-major: score B-frag layout)
__global__ __launch_bounds__(256) void conv_hs(const float* __restrict__ hidden,
                                               unsigned* __restrict__ hs_hi,
                                               unsigned* __restrict__ hs_lo){
    size_t gid = (size_t)blockIdx.x * 256 + threadIdx.x;   // < B*200*64
    float2 h2 = *(const float2*)(hidden + gid * 2);
    hs_hi[gid] = pack_hi2(h2.x, h2.y);
    hs_lo[gid] = pack_hi2(h2.x - hi_of(h2.x), h2.y - hi_of(h2.y));
}

// hidden -> ht[b][d][j2] bf16 hi/lo (transposed, j zero-padded to 224: PV B layout)
__global__ __launch_bounds__(256) void conv_ht(const float* __restrict__ hidden,
                                               unsigned* __restrict__ ht_hi,
                                               unsigned* __restrict__ ht_lo){
    __shared__ float tile[32][33];
    const int bid = blockIdx.x;
    const int b  = bid / 28;
    const int rem = bid % 28;
    const int jt = rem >> 2, dt = rem & 3;    // 7 j-tiles x 4 d-tiles of 32
    const int j0 = jt * 32, d0 = dt * 32;
    const int tt = threadIdx.x;
    #pragma unroll
    for (int rr = 0; rr < 4; ++rr) {
        int j = j0 + (tt >> 5) + rr * 8;
        int d = d0 + (tt & 31);
        tile[(tt >> 5) + rr * 8][tt & 31] =
            (j < NB) ? hidden[((size_t)b * NB + j) * DIMH + d] : 0.0f;
    }
    __syncthreads();
    #pragma unroll
    for (int it = 0; it < 2; ++it) {
        int j2 = it * 8 + (tt & 7);
        int dl = tt >> 3;
        float v0 = tile[2 * j2][dl];
        float v1 = tile[2 * j2 + 1][dl];
        size_t o = ((size_t)b * DIMH + d0 + dl) * KJ2 + (j0 >> 1) + j2;
        ht_hi[o] = pack_hi2(v0, v1);
        ht_lo[o] = pack_hi2(v0 - hi_of(v0), v1 - hi_of(v1));
    }
}

// MODE 2: full MFMA path. MODE 1: f32 score conv + VALU PV + MFMA gate. MODE 0: f32 gate.
template<int MODE>
__global__ __launch_bounds__(TPB, 4) void la_fused(
    const float* __restrict__ hidden,
    const int*   __restrict__ adj,
    const int*   __restrict__ mask,
    const float* __restrict__ a0, const float* __restrict__ a1,
    const float* __restrict__ a2, const float* __restrict__ a3,
    const float* __restrict__ W,  const float* __restrict__ bias,
    const unsigned* __restrict__ wf,
    const unsigned* __restrict__ hs_hi, const unsigned* __restrict__ hs_lo,
    const unsigned* __restrict__ ht_hi, const unsigned* __restrict__ ht_lo,
    float* __restrict__ out)
{
    // LDS diet (r12): hab dropped (A-frags direct from global), scr sized to need.
    // MODE2 total ~15.4KB -> 8 blocks/CU (32 waves, HW max).
    constexpr int SCR_U32 = (MODE == 2) ? 2 * 4 * 116 : 4 * 4 * 128;
    __shared__ float xs[ROWS][208];        // scores -> p; later gate-output buffer
    __shared__ float cop[ROWS][256];       // [0:128)=h_i, [128:256)=o
    __shared__ unsigned scr_u[SCR_U32];    // MODE2: pbf[2][4][116]; else f32 partials
    __shared__ unsigned cbf[2][ROWS][132]; // gate A rows bf16x2

    unsigned* pbf = scr_u;
    float* scrf = (float*)scr_u;           // fallback partials [w][row][128]

    const int t    = threadIdx.x;
    const int lane = t & 63;
    const int r    = t >> 6;
    const int d2   = 2 * lane;
    const int bid  = blockIdx.x;
    const int b    = bid / (NB / ROWS);
    const int i0   = (bid % (NB / ROWS)) * ROWS;

    const float* hb = hidden + (size_t)b * NB * DIMH;

    // ---- stage h_i rows into cop (no barrier needed until first cross-wave read) ----
    for (int idx = t; idx < ROWS * DIMH; idx += TPB) {
        int rr = idx >> 7, d = idx & 127;
        cop[rr][d] = hb[(i0 + rr) * DIMH + d];
    }

    // ---- A-fragments direct from global: lane's row rk=lane&15 -> (rr, k) ----
    short8v Ahi[4], Alo[4];
    {
        const int arow = lane & 15;
        const int rr = arow >> 2, k = arow & 3;
        const float* ap = (k == 0) ? a0 : (k == 1) ? a1 : (k == 2) ? a2 : a3;
        const float* hp  = hb + (size_t)(i0 + rr) * DIMH + (lane >> 4) * 8;
        const float* app = ap + (lane >> 4) * 8;
        #pragma unroll
        for (int ks = 0; ks < 4; ++ks) {
            float4 h0 = *(const float4*)(hp + ks * 32);
            float4 h1 = *(const float4*)(hp + ks * 32 + 4);
            float4 A0 = *(const float4*)(app + ks * 32);
            float4 A1 = *(const float4*)(app + ks * 32 + 4);
            float q0 = h0.x * A0.x, q1 = h0.y * A0.y, q2 = h0.z * A0.z, q3 = h0.w * A0.w;
            float q4 = h1.x * A1.x, q5 = h1.y * A1.y, q6 = h1.z * A1.z, q7 = h1.w * A1.w;
            u32x4 hi4 = { pack_hi2(q0, q1), pack_hi2(q2, q3),
                          pack_hi2(q4, q5), pack_hi2(q6, q7) };
            u32x4 lo4 = { pack_hi2(q0 - hi_of(q0), q1 - hi_of(q1)),
                          pack_hi2(q2 - hi_of(q2), q3 - hi_of(q3)),
                          pack_hi2(q4 - hi_of(q4), q5 - hi_of(q5)),
                          pack_hi2(q6 - hi_of(q6), q7 - hi_of(q7)) };
            Ahi[ks] = __builtin_bit_cast(short8v, hi4);
            Alo[ks] = __builtin_bit_cast(short8v, lo4);
        }
    }

    // ---- score via MFMA ----
    const int jcol = lane & 15;
    const int kgrp = lane >> 4;
    for (int jt = r; jt < NJT; jt += 4) {
        const int jrow = jt * 16 + jcol;
        const int jl   = (jrow < NB) ? jrow : (NB - 1);
        f32x4 acc = {0.f, 0.f, 0.f, 0.f};
        if constexpr (MODE == 2) {
            const unsigned* bh = hs_hi + ((size_t)(b * NB + jl) << 6) + kgrp * 4;
            const unsigned* bl = hs_lo + ((size_t)(b * NB + jl) << 6) + kgrp * 4;
            #pragma unroll
            for (int ks = 0; ks < 4; ++ks) {
                short8v Bh = __builtin_bit_cast(short8v, *(const u32x4*)(bh + ks * 16));
                short8v Bl = __builtin_bit_cast(short8v, *(const u32x4*)(bl + ks * 16));
                acc = __builtin_amdgcn_mfma_f32_16x16x32_bf16(Ahi[ks], Bh, acc, 0, 0, 0);
                acc = __builtin_amdgcn_mfma_f32_16x16x32_bf16(Alo[ks], Bh, acc, 0, 0, 0);
                acc = __builtin_amdgcn_mfma_f32_16x16x32_bf16(Ahi[ks], Bl, acc, 0, 0, 0);
            }
        } else {
            const float* hj = hb + (size_t)jl * DIMH + kgrp * 8;
            #pragma unroll
            for (int ks = 0; ks < 4; ++ks) {
                float4 ra = *(const float4*)(hj + ks * 32);
                float4 rb = *(const float4*)(hj + ks * 32 + 4);
                u32x4 bh = { pack_hi2(ra.x, ra.y), pack_hi2(ra.z, ra.w),
                             pack_hi2(rb.x, rb.y), pack_hi2(rb.z, rb.w) };
                u32x4 bl = { pack_hi2(ra.x - hi_of(ra.x), ra.y - hi_of(ra.y)),
                             pack_hi2(ra.z - hi_of(ra.z), ra.w - hi_of(ra.w)),
                             pack_hi2(rb.x - hi_of(rb.x), rb.y - hi_of(rb.y)),
                             pack_hi2(rb.z - hi_of(rb.z), rb.w - hi_of(rb.w)) };
                short8v Bh = __builtin_bit_cast(short8v, bh);
                short8v Bl = __builtin_bit_cast(short8v, bl);
                acc = __builtin_amdgcn_mfma_f32_16x16x32_bf16(Ahi[ks], Bh, acc, 0, 0, 0);
                acc = __builtin_amdgcn_mfma_f32_16x16x32_bf16(Alo[ks], Bh, acc, 0, 0, 0);
                acc = __builtin_amdgcn_mfma_f32_16x16x32_bf16(Ahi[ks], Bl, acc, 0, 0, 0);
            }
        }
        int kk = adj[(size_t)(b * NB + i0 + kgrp) * NB + jl];
        int mm = mask[b * NB + jl];
        float ev = (kk == 1) ? acc[0] : (kk == 2) ? acc[1] :
                   (kk == 3) ? acc[2] : (kk == 4) ? acc[3] : 0.0f;
        ev = (ev >= 0.0f) ? ev : 0.2f * ev;            // leaky relu 0.2
        float x = ev * 0.1f;                           // * (alpha-1)
        if (mm == 0)     x = -INFINITY;
        if (jrow >= NB)  x = -INFINITY;
        xs[kgrp][jrow] = x;
    }
    __syncthreads();                                   // B: scores visible

    // ---- entmax bisection: wave r owns row i0+r ----
    float x0 = xs[r][lane];
    float x1 = xs[r][lane + 64];
    float x2 = xs[r][lane + 128];
    float x3 = (lane < 16) ? xs[r][192 + lane] : -INFINITY;

    float mx  = wmax_dpp(fmaxf(fmaxf(x0, x1), fmaxf(x2, x3)));
    float tau = mx - 1.0f;
    #define P10(v, tt) ({ float z_ = fmaxf((v) - (tt), 0.f); float z2 = z_*z_; float z4 = z2*z2; float z8 = z4*z4; z8*z2; })
    float s0 = P10(x0, tau) + P10(x1, tau) + P10(x2, tau) + P10(x3, tau);
    float f_lo = wsum_dpp(s0) - 1.0f;                  // captured once (matches ref)
    float dm   = (mx - 0.58870401f) - tau;             // (1/200)^0.1

    for (int itn = 0; itn < NITER; ++itn) {
        dm *= 0.5f;
        float tm = tau + dm;
        float s = P10(x0, tm) + P10(x1, tm) + P10(x2, tm) + P10(x3, tm);
        float fm = wsum_dpp(s) - 1.0f;
        if (fm * f_lo >= 0.0f) tau = tm;
    }
    float p0 = P10(x0, tau);
    float p1 = P10(x1, tau);
    float p2 = P10(x2, tau);
    float p3 = P10(x3, tau);
    #undef P10
    float sinv = 1.0f / wsum_dpp(p0 + p1 + p2 + p3);   // ensure_sum_one
    xs[r][lane]       = p0 * sinv;                     // wave-local write-back
    xs[r][lane + 64]  = p1 * sinv;
    xs[r][lane + 128] = p2 * sinv;
    if (lane < 16) xs[r][192 + lane] = p3 * sinv;

    // ================= PV =================
    if constexpr (MODE == 2) {
        // pbf row r built wave-locally from own xs row (in-wave LDS ordering, no barrier)
        for (int k2 = lane; k2 < KJ2; k2 += 64) {
            int j = 2 * k2;
            float v0 = (j < 208)     ? xs[r][j]     : 0.0f;
            float v1 = (j + 1 < 208) ? xs[r][j + 1] : 0.0f;
            pbf[r * 116 + k2]           = pack_hi2(v0, v1);
            pbf[4 * 116 + r * 116 + k2] = pack_hi2(v0 - hi_of(v0), v1 - hi_of(v1));
        }
        __syncthreads();                               // C: pbf all rows visible

        // O = P x H via MFMA: wave r does n-tiles 2r, 2r+1 (dims [32r,32r+32))
        f32x4 av0 = {0.f,0.f,0.f,0.f}, av1 = {0.f,0.f,0.f,0.f};
        const int prow = lane & 3;                     // duplicated A rows
        const int au   = (lane >> 4) * 4;
        const int dc0  = 32 * r + (lane & 15);
        const size_t base0 = ((size_t)(b * DIMH + dc0)) * KJ2 + au;
        const size_t base1 = base0 + 16 * KJ2;
        #pragma unroll
        for (int ks = 0; ks < 7; ++ks) {
            short8v Ph = __builtin_bit_cast(short8v, *(const u32x4*)&pbf[prow * 116 + ks * 16 + au]);
            short8v Pl = __builtin_bit_cast(short8v, *(const u32x4*)&pbf[4 * 116 + prow * 116 + ks * 16 + au]);
            short8v B0h = __builtin_bit_cast(short8v, *(const u32x4*)(ht_hi + base0 + ks * 16));
            short8v B0l = __builtin_bit_cast(short8v, *(const u32x4*)(ht_lo + base0 + ks * 16));
            short8v B1h = __builtin_bit_cast(short8v, *(const u32x4*)(ht_hi + base1 + ks * 16));
            short8v B1l = __builtin_bit_cast(short8v, *(const u32x4*)(ht_lo + base1 + ks * 16));
            av0 = __builtin_amdgcn_mfma_f32_16x16x32_bf16(Ph, B0h, av0, 0, 0, 0);
            av0 = __builtin_amdgcn_mfma_f32_16x16x32_bf16(Pl, B0h, av0, 0, 0, 0);
            av0 = __builtin_amdgcn_mfma_f32_16x16x32_bf16(Ph, B0l, av0, 0, 0, 0);
            av1 = __builtin_amdgcn_mfma_f32_16x16x32_bf16(Ph, B1h, av1, 0, 0, 0);
            av1 = __builtin_amdgcn_mfma_f32_16x16x32_bf16(Pl, B1h, av1, 0, 0, 0);
            av1 = __builtin_amdgcn_mfma_f32_16x16x32_bf16(Ph, B1l, av1, 0, 0, 0);
        }
        if (lane < 16) {
            #pragma unroll
            for (int q = 0; q < 4; ++q) {
                cop[q][DIMH + 32 * r + lane]      = av0[q];
                cop[q][DIMH + 32 * r + 16 + lane] = av1[q];
            }
        }
        __syncthreads();                               // E: o rows complete
    } else {
        __syncthreads();                               // C (p visible cross-wave)
        const int J0 = r * 50;
        float pj0 = (lane < 50) ? xs[0][J0 + lane] : 0.f;
        float pj1 = (lane < 50) ? xs[1][J0 + lane] : 0.f;
        float pj2 = (lane < 50) ? xs[2][J0 + lane] : 0.f;
        float pj3 = (lane < 50) ? xs[3][J0 + lane] : 0.f;
        float2 ov0 = {0.f,0.f}, ov1 = {0.f,0.f}, ov2 = {0.f,0.f}, ov3 = {0.f,0.f};
        const float* hjb = hb + (size_t)J0 * DIMH + d2;
        #pragma unroll 5
        for (int jj = 0; jj < 50; ++jj) {
            float2 hv = *(const float2*)(hjb + jj * DIMH);
            float c0 = rdlane(pj0, jj), c1 = rdlane(pj1, jj);
            float c2 = rdlane(pj2, jj), c3 = rdlane(pj3, jj);
            ov0.x = fmaf(c0, hv.x, ov0.x); ov0.y = fmaf(c0, hv.y, ov0.y);
            ov1.x = fmaf(c1, hv.x, ov1.x); ov1.y = fmaf(c1, hv.y, ov1.y);
            ov2.x = fmaf(c2, hv.x, ov2.x); ov2.y = fmaf(c2, hv.y, ov2.y);
            ov3.x = fmaf(c3, hv.x, ov3.x); ov3.y = fmaf(c3, hv.y, ov3.y);
        }
        *(float2*)&scrf[(r * 4 + 0) * DIMH + d2] = ov0;
        *(float2*)&scrf[(r * 4 + 1) * DIMH + d2] = ov1;
        *(float2*)&scrf[(r * 4 + 2) * DIMH + d2] = ov2;
        *(float2*)&scrf[(r * 4 + 3) * DIMH + d2] = ov3;
        __syncthreads();                               // D
        float2 q0 = *(const float2*)&scrf[(0 * 4 + r) * DIMH + d2];
        float2 q1 = *(const float2*)&scrf[(1 * 4 + r) * DIMH + d2];
        float2 q2 = *(const float2*)&scrf[(2 * 4 + r) * DIMH + d2];
        float2 q3 = *(const float2*)&scrf[(3 * 4 + r) * DIMH + d2];
        float2 o;
        o.x = (q0.x + q1.x) + (q2.x + q3.x);
        o.y = (q0.y + q1.y) + (q2.y + q3.y);
        *(float2*)&cop[r][DIMH + d2] = o;
        __syncthreads();                               // E
    }

    float2 ov = *(const float2*)&cop[r][DIMH + d2];
    float2 gres;

    // ================= gate =================
    if constexpr (MODE >= 1) {
        float hx = cop[r][d2], hy = cop[r][d2 + 1];
        cbf[0][r][lane]      = pack_hi2(hx, hy);
        cbf[1][r][lane]      = pack_hi2(hx - hi_of(hx), hy - hi_of(hy));
        cbf[0][r][64 + lane] = pack_hi2(ov.x, ov.y);
        cbf[1][r][64 + lane] = pack_hi2(ov.x - hi_of(ov.x), ov.y - hi_of(ov.y));
        __syncthreads();                               // F
        f32x4 ga0 = {0.f,0.f,0.f,0.f}, ga1 = {0.f,0.f,0.f,0.f};
        const int arow = lane & 3;
        const int au   = (lane >> 4) * 4;
        #pragma unroll
        for (int ks = 0; ks < 8; ++ks) {
            short8v Ah = __builtin_bit_cast(short8v, *(const u32x4*)&cbf[0][arow][ks * 16 + au]);
            short8v Al = __builtin_bit_cast(short8v, *(const u32x4*)&cbf[1][arow][ks * 16 + au]);
            const unsigned bi0 = (((2 * r) * 8 + ks) * 64 + lane) * 4;
            const unsigned bi1 = (((2 * r + 1) * 8 + ks) * 64 + lane) * 4;
            short8v Bh0 = __builtin_bit_cast(short8v, *(const u32x4*)&wf[bi0]);
            short8v Bl0 = __builtin_bit_cast(short8v, *(const u32x4*)&wf[WF_U32 / 2 + bi0]);
            short8v Bh1 = __builtin_bit_cast(short8v, *(const u32x4*)&wf[bi1]);
            short8v Bl1 = __builtin_bit_cast(short8v, *(const u32x4*)&wf[WF_U32 / 2 + bi1]);
            ga0 = __builtin_amdgcn_mfma_f32_16x16x32_bf16(Ah, Bh0, ga0, 0, 0, 0);
            ga0 = __builtin_amdgcn_mfma_f32_16x16x32_bf16(Al, Bh0, ga0, 0, 0, 0);
            ga0 = __builtin_amdgcn_mfma_f32_16x16x32_bf16(Ah, Bl0, ga0, 0, 0, 0);
            ga1 = __builtin_amdgcn_mfma_f32_16x16x32_bf16(Ah, Bh1, ga1, 0, 0, 0);
            ga1 = __builtin_amdgcn_mfma_f32_16x16x32_bf16(Al, Bh1, ga1, 0, 0, 0);
            ga1 = __builtin_amdgcn_mfma_f32_16x16x32_bf16(Ah, Bl1, ga1, 0, 0, 0);
        }
        if (lane < 16) {
            #pragma unroll
            for (int m = 0; m < 4; ++m) {
                xs[m][(2 * r) * 16 + lane]     = ga0[m];   // xs reused as gbuf
                xs[m][(2 * r + 1) * 16 + lane] = ga1[m];
            }
        }
        __syncthreads();                               // G
        gres.x = xs[r][d2];
        gres.y = xs[r][d2 + 1];
    } else {
        float cv0 = cop[0][64 * r + lane];
        float cv1 = cop[1][64 * r + lane];
        float cv2 = cop[2][64 * r + lane];
        float cv3 = cop[3][64 * r + lane];
        float2 gv0 = {0.f,0.f}, gv1 = {0.f,0.f}, gv2 = {0.f,0.f}, gv3 = {0.f,0.f};
        const float* wb = W + (size_t)(64 * r) * DIMH + d2;
        #pragma unroll 8
        for (int ee = 0; ee < 64; ++ee) {
            float2 wv = *(const float2*)(wb + ee * DIMH);
            float c0 = rdlane(cv0, ee), c1 = rdlane(cv1, ee);
            float c2 = rdlane(cv2, ee), c3 = rdlane(cv3, ee);
            gv0.x = fmaf(c0, wv.x, gv0.x); gv0.y = fmaf(c0, wv.y, gv0.y);
            gv1.x = fmaf(c1, wv.x, gv1.x); gv1.y = fmaf(c1, wv.y, gv1.y);
            gv2.x = fmaf(c2, wv.x, gv2.x); gv2.y = fmaf(c2, wv.y, gv2.y);
            gv3.x = fmaf(c3, wv.x, gv3.x); gv3.y = fmaf(c3, wv.y, gv3.y);
        }
        *(float2*)&scrf[(r * 4 + 0) * DIMH + d2] = gv0;
        *(float2*)&scrf[(r * 4 + 1) * DIMH + d2] = gv1;
        *(float2*)&scrf[(r * 4 + 2) * DIMH + d2] = gv2;
        *(float2*)&scrf[(r * 4 + 3) * DIMH + d2] = gv3;
        __syncthreads();                               // F
        float2 q0 = *(const float2*)&scrf[(0 * 4 + r) * DIMH + d2];
        float2 q1 = *(const float2*)&scrf[(1 * 4 + r) * DIMH + d2];
        float2 q2 = *(const float2*)&scrf[(2 * 4 + r) * DIMH + d2];
        float2 q3 = *(const float2*)&scrf[(3 * 4 + r) * DIMH + d2];
        gres.x = (q0.x + q1.x) + (q2.x + q3.x);
        gres.y = (q0.y + q1.y) + (q2.y + q3.y);
    }

    // ---- final: bias, sigmoid, mix, store ----
    {
        float2 bv = *(const float2*)(bias + d2);
        float gx = gres.x + bv.x;
        float gy = gres.y + bv.y;
        float sgx = 1.0f / (1.0f + __expf(-gx));
        float sgy = 1.0f / (1.0f + __expf(-gy));
        float2 hf = *(const float2*)&cop[r][d2];
        const size_t gi = (size_t)(b * NB + i0 + r) * DIMH;
        float2 res;
        res.x = sgx * ov.x + (1.0f - sgx) * hf.x;
        res.y = sgy * ov.y + (1.0f - sgy) * hf.y;
        *(float2*)(out + gi + d2) = res;
    }
}

extern "C" void kernel_launch(void* const* d_in, const int* in_sizes, int n_in,
                              void* d_out, int out_size, void* d_ws, size_t ws_size,
                              hipStream_t stream)
{
    const float* hidden = (const float*)d_in[0];
    const int*   adj    = (const int*)d_in[1];
    const int*   mask   = (const int*)d_in[2];
    const float* a0     = (const float*)d_in[3];
    const float* a1     = (const float*)d_in[4];
    const float* a2     = (const float*)d_in[5];
    const float* a3     = (const float*)d_in[6];
    const float* W      = (const float*)d_in[7];
    const float* bias   = (const float*)d_in[8];
    float* out = (float*)d_out;

    const int B = in_sizes[0] / (NB * DIMH);   // 256
    dim3 grid(B * (NB / ROWS));

    const size_t hsN = (size_t)B * NB * 64;         // u32 per hs table
    const size_t htN = (size_t)B * DIMH * KJ2;      // u32 per ht table
    const size_t fullU32 = (size_t)WF_U32 + 2 * hsN + 2 * htN;

    if (ws_size >= fullU32 * sizeof(unsigned)) {
        unsigned* wf    = (unsigned*)d_ws;
        unsigned* hs_hi = wf + WF_U32;
        unsigned* hs_lo = hs_hi + hsN;
        unsigned* ht_hi = hs_lo + hsN;
        unsigned* ht_lo = ht_hi + htN;
        conv_w<<<64, 64, 0, stream>>>(W, wf);
        conv_hs<<<(unsigned)(hsN / 256), 256, 0, stream>>>(hidden, hs_hi, hs_lo);
        conv_ht<<<B * 28, 256, 0, stream>>>(hidden, ht_hi, ht_lo);
        la_fused<2><<<grid, TPB, 0, stream>>>(hidden, adj, mask, a0, a1, a2, a3,
                                              W, bias, wf, hs_hi, hs_lo, ht_hi, ht_lo, out);
    } else if (ws_size >= (size_t)WF_U32 * sizeof(unsigned)) {
        unsigned* wf = (unsigned*)d_ws;
        conv_w<<<64, 64, 0, stream>>>(W, wf);
        la_fused<1><<<grid, TPB, 0, stream>>>(hidden, adj, mask, a0, a1, a2, a3,
                                              W, bias, wf, nullptr, nullptr, nullptr, nullptr, out);
    } else {
        la_fused<0><<<grid, TPB, 0, stream>>>(hidden, adj, mask, a0, a1, a2, a3,
                                              W, bias, nullptr, nullptr, nullptr, nullptr, nullptr, out);
    }
}

// Round 13
// 277.772 us; speedup vs baseline: 1.3481x; 1.3481x over previous
//
#include <hip/hip_runtime.h>
#include <math.h>

#define NB    200
#define DIMH  128
#define TPB8  512
#define ROWS8 8
#define NITER 12   // tau err 0.411*2^-12 ~ 1e-4 -> p err ~1e-3, threshold 8.5e-2
#define NJT   13   // j-tiles of 16 covering 208
#define KJ2   112  // padded j-pairs for PV (224 j's)

typedef __attribute__((ext_vector_type(8))) short  short8v;
typedef __attribute__((ext_vector_type(4))) float  f32x4;
typedef __attribute__((ext_vector_type(4))) unsigned u32x4;

#define WF_U32 32768   // W-frag table: 8nt*8ks*64lane*4 u32 (hi) + same (lo)

__device__ __forceinline__ unsigned pack_hi2(float a, float b){
    return (__builtin_bit_cast(unsigned, a) >> 16) |
           (__builtin_bit_cast(unsigned, b) & 0xFFFF0000u);
}
__device__ __forceinline__ float hi_of(float x){
    return __builtin_bit_cast(float, __builtin_bit_cast(unsigned, x) & 0xFFFF0000u);
}
__device__ __forceinline__ float rdlane(float v, int l){
    return __builtin_bit_cast(float,
        __builtin_amdgcn_readlane(__builtin_bit_cast(int, v), l));
}
__device__ __forceinline__ float wsum_dpp(float v){
#define DPP_ADD(ctrl, rmask)                                                     \
    {                                                                            \
        int t_ = __builtin_amdgcn_update_dpp(0, __builtin_bit_cast(int, v),      \
                                             ctrl, rmask, 0xf, false);           \
        v += __builtin_bit_cast(float, t_);                                      \
    }
    DPP_ADD(0x111, 0xf)
    DPP_ADD(0x112, 0xf)
    DPP_ADD(0x114, 0xf)
    DPP_ADD(0x118, 0xf)
    DPP_ADD(0x142, 0xa)
    DPP_ADD(0x143, 0xc)
#undef DPP_ADD
    return rdlane(v, 63);
}
__device__ __forceinline__ float wmax_dpp(float v){
#define DPP_MAX(ctrl, rmask)                                                     \
    {                                                                            \
        int t_ = __builtin_amdgcn_update_dpp(__builtin_bit_cast(int, v),         \
                                             __builtin_bit_cast(int, v),         \
                                             ctrl, rmask, 0xf, false);           \
        v = fmaxf(v, __builtin_bit_cast(float, t_));                             \
    }
    DPP_MAX(0x111, 0xf)
    DPP_MAX(0x112, 0xf)
    DPP_MAX(0x114, 0xf)
    DPP_MAX(0x118, 0xf)
    DPP_MAX(0x142, 0xa)
    DPP_MAX(0x143, 0xc)
#undef DPP_MAX
    return rdlane(v, 63);
}

// One-time W -> bf16 hi/lo fragment table (gate MFMA B layout). Validated r10/r11.
__global__ __launch_bounds__(64) void conv_w(const float* __restrict__ W,
                                             unsigned* __restrict__ wf){
    const int lane = threadIdx.x;
    const int ks = blockIdx.x & 7, nt = blockIdx.x >> 3;
    const int krow = ks * 32 + (lane >> 4) * 8;
    const int col  = nt * 16 + (lane & 15);
    unsigned hi[4], lo[4];
    #pragma unroll
    for (int q2 = 0; q2 < 4; ++q2) {
        float v0 = W[(size_t)(krow + 2 * q2) * DIMH + col];
        float v1 = W[(size_t)(krow + 2 * q2 + 1) * DIMH + col];
        hi[q2] = pack_hi2(v0, v1);
        lo[q2] = pack_hi2(v0 - hi_of(v0), v1 - hi_of(v1));
    }
    const unsigned base = (blockIdx.x * 64 + lane) * 4;
    *(u32x4*)&wf[base]              = (u32x4){hi[0], hi[1], hi[2], hi[3]};
    *(u32x4*)&wf[WF_U32 / 2 + base] = (u32x4){lo[0], lo[1], lo[2], lo[3]};
}

// hidden -> hs[b][j][d2] bf16 hi/lo (score B layout). Validated r11.
__global__ __launch_bounds__(256) void conv_hs(const float* __restrict__ hidden,
                                               unsigned* __restrict__ hs_hi,
                                               unsigned* __restrict__ hs_lo){
    size_t gid = (size_t)blockIdx.x * 256 + threadIdx.x;
    float2 h2 = *(const float2*)(hidden + gid * 2);
    hs_hi[gid] = pack_hi2(h2.x, h2.y);
    hs_lo[gid] = pack_hi2(h2.x - hi_of(h2.x), h2.y - hi_of(h2.y));
}

// hidden -> ht[b][d][j2] bf16 hi/lo (transposed, padded to 224 j: PV B layout). Validated r11.
__global__ __launch_bounds__(256) void conv_ht(const float* __restrict__ hidden,
                                               unsigned* __restrict__ ht_hi,
                                               unsigned* __restrict__ ht_lo){
    __shared__ float tile[32][33];
    const int bid = blockIdx.x;
    const int b  = bid / 28;
    const int rem = bid % 28;
    const int jt = rem >> 2, dt = rem & 3;
    const int j0 = jt * 32, d0 = dt * 32;
    const int tt = threadIdx.x;
    #pragma unroll
    for (int rr = 0; rr < 4; ++rr) {
        int j = j0 + (tt >> 5) + rr * 8;
        int d = d0 + (tt & 31);
        tile[(tt >> 5) + rr * 8][tt & 31] =
            (j < NB) ? hidden[((size_t)b * NB + j) * DIMH + d] : 0.0f;
    }
    __syncthreads();
    #pragma unroll
    for (int it = 0; it < 2; ++it) {
        int j2 = it * 8 + (tt & 7);
        int dl = tt >> 3;
        float v0 = tile[2 * j2][dl];
        float v1 = tile[2 * j2 + 1][dl];
        size_t o = ((size_t)b * DIMH + d0 + dl) * KJ2 + (j0 >> 1) + j2;
        ht_hi[o] = pack_hi2(v0, v1);
        ht_lo[o] = pack_hi2(v0 - hi_of(v0), v1 - hi_of(v1));
    }
}

// r13: 8 rows/block, 8 waves. Per-block fixed costs amortized 2x vs the 4-row kernel.
// PV/gate MFMA per wave halved (one n-tile each). hab LDS staging restored (r12's
// global A-frag build was the regression). __launch_bounds__(512,4): 128-VGPR cap
// (the proven no-spill regime). WRITE_SIZE tripwire: exactly 25600 KB.
__global__ __launch_bounds__(TPB8, 4) void la_fused8(
    const float* __restrict__ hidden,
    const int*   __restrict__ adj,
    const int*   __restrict__ mask,
    const float* __restrict__ a0, const float* __restrict__ a1,
    const float* __restrict__ a2, const float* __restrict__ a3,
    const float* __restrict__ bias,
    const unsigned* __restrict__ wf,
    const unsigned* __restrict__ hs_hi, const unsigned* __restrict__ hs_lo,
    const unsigned* __restrict__ ht_hi, const unsigned* __restrict__ ht_lo,
    float* __restrict__ out)
{
    __shared__ unsigned hab[2][32][68];    // ha bf16x2 [hi/lo][rk=8rows x 4k][d2]
    __shared__ float xs[ROWS8][208];       // scores -> p; later gate-output buffer
    __shared__ float cop[ROWS8][256];      // [0:128)=h_i, [128:256)=o
    __shared__ unsigned pbf[2 * ROWS8 * 116]; // P bf16 hi/lo
    __shared__ unsigned cbf[2][ROWS8][132];   // gate A rows bf16x2

    const int t    = threadIdx.x;
    const int lane = t & 63;
    const int r    = t >> 6;               // wave id 0..7 == row owned
    const int d2   = 2 * lane;
    const int bid  = blockIdx.x;
    const int b    = bid / (NB / ROWS8);   // NB/ROWS8 = 25
    const int i0   = (bid % (NB / ROWS8)) * ROWS8;

    const float* hb = hidden + (size_t)b * NB * DIMH;

    // ---- stage h_i rows (cop) and bf16 hi/lo ha table (coalesced) ----
    for (int idx = t; idx < ROWS8 * DIMH; idx += TPB8) {
        int rr = idx >> 7, d = idx & 127;
        cop[rr][d] = hb[(i0 + rr) * DIMH + d];
    }
    for (int s = t; s < 32 * 64; s += TPB8) {
        int rk = s >> 6, dd = s & 63;
        int rr = rk >> 2, k = rk & 3;
        int d  = dd * 2;
        const float* ap = (k == 0) ? a0 : (k == 1) ? a1 : (k == 2) ? a2 : a3;
        float h0 = hb[(i0 + rr) * DIMH + d];
        float h1 = hb[(i0 + rr) * DIMH + d + 1];
        float q0 = h0 * ap[d];
        float q1 = h1 * ap[d + 1];
        hab[0][rk][dd] = pack_hi2(q0, q1);
        hab[1][rk][dd] = pack_hi2(q0 - hi_of(q0), q1 - hi_of(q1));
    }
    __syncthreads();                                   // A

    // ---- A-fragments: wave owns tile = r&1 (rk rows tile*16..tile*16+15) ----
    const int tile = r & 1;
    const int qjt  = r >> 1;
    short8v Ahi[4], Alo[4];
    {
        const int arow = tile * 16 + (lane & 15);
        const int au   = (lane >> 4) * 4;
        #pragma unroll
        for (int ks = 0; ks < 4; ++ks) {
            Ahi[ks] = __builtin_bit_cast(short8v, *(const u32x4*)&hab[0][arow][ks * 16 + au]);
            Alo[ks] = __builtin_bit_cast(short8v, *(const u32x4*)&hab[1][arow][ks * 16 + au]);
        }
    }

    // ---- score via MFMA: wave handles (tile, jt = qjt, qjt+4, ...) ----
    const int jcol = lane & 15;
    const int kgrp = lane >> 4;
    for (int jt = qjt; jt < NJT; jt += 4) {
        const int jrow = jt * 16 + jcol;
        const int jl   = (jrow < NB) ? jrow : (NB - 1);
        f32x4 acc = {0.f, 0.f, 0.f, 0.f};
        const unsigned* bh = hs_hi + ((size_t)(b * NB + jl) << 6) + kgrp * 4;
        const unsigned* bl = hs_lo + ((size_t)(b * NB + jl) << 6) + kgrp * 4;
        #pragma unroll
        for (int ks = 0; ks < 4; ++ks) {
            short8v Bh = __builtin_bit_cast(short8v, *(const u32x4*)(bh + ks * 16));
            short8v Bl = __builtin_bit_cast(short8v, *(const u32x4*)(bl + ks * 16));
            acc = __builtin_amdgcn_mfma_f32_16x16x32_bf16(Ahi[ks], Bh, acc, 0, 0, 0);
            acc = __builtin_amdgcn_mfma_f32_16x16x32_bf16(Alo[ks], Bh, acc, 0, 0, 0);
            acc = __builtin_amdgcn_mfma_f32_16x16x32_bf16(Ahi[ks], Bl, acc, 0, 0, 0);
        }
        const int orow = tile * 4 + kgrp;              // 0..7
        int kk = adj[(size_t)(b * NB + i0 + orow) * NB + jl];
        int mm = mask[b * NB + jl];
        float ev = (kk == 1) ? acc[0] : (kk == 2) ? acc[1] :
                   (kk == 3) ? acc[2] : (kk == 4) ? acc[3] : 0.0f;
        ev = (ev >= 0.0f) ? ev : 0.2f * ev;            // leaky relu 0.2
        float x = ev * 0.1f;                           // * (alpha-1)
        if (mm == 0)     x = -INFINITY;
        if (jrow >= NB)  x = -INFINITY;                // pad cols 200..207
        xs[orow][jrow] = x;
    }
    __syncthreads();                                   // B

    // ---- entmax bisection: wave r owns row i0+r ----
    float x0 = xs[r][lane];
    float x1 = xs[r][lane + 64];
    float x2 = xs[r][lane + 128];
    float x3 = (lane < 16) ? xs[r][192 + lane] : -INFINITY;

    float mx  = wmax_dpp(fmaxf(fmaxf(x0, x1), fmaxf(x2, x3)));
    float tau = mx - 1.0f;
    #define P10(v, tt) ({ float z_ = fmaxf((v) - (tt), 0.f); float z2 = z_*z_; float z4 = z2*z2; float z8 = z4*z4; z8*z2; })
    float s0 = P10(x0, tau) + P10(x1, tau) + P10(x2, tau) + P10(x3, tau);
    float f_lo = wsum_dpp(s0) - 1.0f;                  // captured once (matches ref)
    float dm   = (mx - 0.58870401f) - tau;             // (1/200)^0.1

    for (int itn = 0; itn < NITER; ++itn) {
        dm *= 0.5f;
        float tm = tau + dm;
        float s = P10(x0, tm) + P10(x1, tm) + P10(x2, tm) + P10(x3, tm);
        float fm = wsum_dpp(s) - 1.0f;
        if (fm * f_lo >= 0.0f) tau = tm;
    }
    float p0 = P10(x0, tau);
    float p1 = P10(x1, tau);
    float p2 = P10(x2, tau);
    float p3 = P10(x3, tau);
    #undef P10
    float sinv = 1.0f / wsum_dpp(p0 + p1 + p2 + p3);   // ensure_sum_one
    xs[r][lane]       = p0 * sinv;                     // wave-local write-back
    xs[r][lane + 64]  = p1 * sinv;
    xs[r][lane + 128] = p2 * sinv;
    if (lane < 16) xs[r][192 + lane] = p3 * sinv;

    // ---- pbf row r built wave-locally (no barrier: own row) ----
    for (int k2 = lane; k2 < KJ2; k2 += 64) {
        int j = 2 * k2;
        float v0 = (j < 208)     ? xs[r][j]     : 0.0f;
        float v1 = (j + 1 < 208) ? xs[r][j + 1] : 0.0f;
        pbf[r * 116 + k2]                = pack_hi2(v0, v1);
        pbf[ROWS8 * 116 + r * 116 + k2]  = pack_hi2(v0 - hi_of(v0), v1 - hi_of(v1));
    }
    __syncthreads();                                   // C: all pbf rows visible

    // ---- PV via MFMA: wave r does n-tile r (dims [16r,16r+16)); A rows dup x2 ----
    {
        f32x4 av = {0.f, 0.f, 0.f, 0.f};
        const int prow = lane & 7;
        const int au   = (lane >> 4) * 4;
        const int dc   = 16 * r + (lane & 15);
        const size_t base = ((size_t)(b * DIMH + dc)) * KJ2 + au;
        #pragma unroll
        for (int ks = 0; ks < 7; ++ks) {
            short8v Ph = __builtin_bit_cast(short8v, *(const u32x4*)&pbf[prow * 116 + ks * 16 + au]);
            short8v Pl = __builtin_bit_cast(short8v, *(const u32x4*)&pbf[ROWS8 * 116 + prow * 116 + ks * 16 + au]);
            short8v Bh = __builtin_bit_cast(short8v, *(const u32x4*)(ht_hi + base + ks * 16));
            short8v Bl = __builtin_bit_cast(short8v, *(const u32x4*)(ht_lo + base + ks * 16));
            av = __builtin_amdgcn_mfma_f32_16x16x32_bf16(Ph, Bh, av, 0, 0, 0);
            av = __builtin_amdgcn_mfma_f32_16x16x32_bf16(Pl, Bh, av, 0, 0, 0);
            av = __builtin_amdgcn_mfma_f32_16x16x32_bf16(Ph, Bl, av, 0, 0, 0);
        }
        // D row m = (lane>>4)*4+reg; actual P-row = m&7; lanes<32 cover rows 0..7 once
        if (lane < 32) {
            const int rbase = (lane >> 4) * 4;
            #pragma unroll
            for (int q = 0; q < 4; ++q)
                cop[rbase + q][DIMH + 16 * r + (lane & 15)] = av[q];
        }
    }
    __syncthreads();                                   // E: o rows complete

    float2 ovv = *(const float2*)&cop[r][DIMH + d2];

    // ---- gate via MFMA: cbf rows = [h_i | o] bf16 hi/lo; wave r does n-tile r ----
    {
        float hx = cop[r][d2], hy = cop[r][d2 + 1];
        cbf[0][r][lane]      = pack_hi2(hx, hy);
        cbf[1][r][lane]      = pack_hi2(hx - hi_of(hx), hy - hi_of(hy));
        cbf[0][r][64 + lane] = pack_hi2(ovv.x, ovv.y);
        cbf[1][r][64 + lane] = pack_hi2(ovv.x - hi_of(ovv.x), ovv.y - hi_of(ovv.y));
    }
    __syncthreads();                                   // F

    {
        f32x4 ga = {0.f, 0.f, 0.f, 0.f};
        const int arow = lane & 7;
        const int au   = (lane >> 4) * 4;
        #pragma unroll
        for (int ks = 0; ks < 8; ++ks) {
            short8v Ah = __builtin_bit_cast(short8v, *(const u32x4*)&cbf[0][arow][ks * 16 + au]);
            short8v Al = __builtin_bit_cast(short8v, *(const u32x4*)&cbf[1][arow][ks * 16 + au]);
            const unsigned bi = ((r * 8 + ks) * 64 + lane) * 4;
            short8v Bh = __builtin_bit_cast(short8v, *(const u32x4*)&wf[bi]);
            short8v Bl = __builtin_bit_cast(short8v, *(const u32x4*)&wf[WF_U32 / 2 + bi]);
            ga = __builtin_amdgcn_mfma_f32_16x16x32_bf16(Ah, Bh, ga, 0, 0, 0);
            ga = __builtin_amdgcn_mfma_f32_16x16x32_bf16(Al, Bh, ga, 0, 0, 0);
            ga = __builtin_amdgcn_mfma_f32_16x16x32_bf16(Ah, Bl, ga, 0, 0, 0);
        }
        if (lane < 32) {                               // rows 0..7 once (xs = gbuf)
            const int rbase = (lane >> 4) * 4;
            #pragma unroll
            for (int q = 0; q < 4; ++q)
                xs[rbase + q][16 * r + (lane & 15)] = ga[q];
        }
    }
    __syncthreads();                                   // G

    // ---- final: bias, sigmoid, mix, store ----
    {
        float2 bv = *(const float2*)(bias + d2);
        float gx = xs[r][d2]     + bv.x;
        float gy = xs[r][d2 + 1] + bv.y;
        float sgx = 1.0f / (1.0f + __expf(-gx));
        float sgy = 1.0f / (1.0f + __expf(-gy));
        float2 hf = *(const float2*)&cop[r][d2];
        const size_t gi = (size_t)(b * NB + i0 + r) * DIMH;
        float2 res;
        res.x = sgx * ovv.x + (1.0f - sgx) * hf.x;
        res.y = sgy * ovv.y + (1.0f - sgy) * hf.y;
        *(float2*)(out + gi + d2) = res;
    }
}

// ---------------- fallback 4-row kernel (modes 1/0), r11-validated structure ----------------
#define ROWS  4
#define TPB   256
template<int MODE>
__global__ __launch_bounds__(TPB, 4) void la_fused(
    const float* __restrict__ hidden,
    const int*   __restrict__ adj,
    const int*   __restrict__ mask,
    const float* __restrict__ a0, const float* __restrict__ a1,
    const float* __restrict__ a2, const float* __restrict__ a3,
    const float* __restrict__ W,  const float* __restrict__ bias,
    const unsigned* __restrict__ wf,
    float* __restrict__ out)
{
    __shared__ unsigned hab[2][16][68];
    __shared__ float xs[ROWS][208];
    __shared__ float cop[ROWS][256];
    __shared__ float scrf[ROWS * ROWS * DIMH];
    __shared__ unsigned cbf[2][ROWS][132];

    const int t    = threadIdx.x;
    const int lane = t & 63;
    const int r    = t >> 6;
    const int d2   = 2 * lane;
    const int bid  = blockIdx.x;
    const int b    = bid / (NB / ROWS);
    const int i0   = (bid % (NB / ROWS)) * ROWS;

    const float* hb = hidden + (size_t)b * NB * DIMH;

    for (int idx = t; idx < ROWS * DIMH; idx += TPB) {
        int rr = idx >> 7, d = idx & 127;
        cop[rr][d] = hb[(i0 + rr) * DIMH + d];
    }
    for (int s = t; s < 16 * 64; s += TPB) {
        int rk = s >> 6, dd = s & 63;
        int rr = rk >> 2, k = rk & 3;
        int d  = dd * 2;
        const float* ap = (k == 0) ? a0 : (k == 1) ? a1 : (k == 2) ? a2 : a3;
        float h0 = hb[(i0 + rr) * DIMH + d];
        float h1 = hb[(i0 + rr) * DIMH + d + 1];
        float q0 = h0 * ap[d];
        float q1 = h1 * ap[d + 1];
        hab[0][rk][dd] = pack_hi2(q0, q1);
        hab[1][rk][dd] = pack_hi2(q0 - hi_of(q0), q1 - hi_of(q1));
    }
    __syncthreads();

    short8v Ahi[4], Alo[4];
    {
        const int arow = lane & 15;
        const int au   = (lane >> 4) * 4;
        #pragma unroll
        for (int ks = 0; ks < 4; ++ks) {
            Ahi[ks] = __builtin_bit_cast(short8v, *(const u32x4*)&hab[0][arow][ks * 16 + au]);
            Alo[ks] = __builtin_bit_cast(short8v, *(const u32x4*)&hab[1][arow][ks * 16 + au]);
        }
    }

    const int jcol = lane & 15;
    const int kgrp = lane >> 4;
    for (int jt = r; jt < NJT; jt += 4) {
        const int jrow = jt * 16 + jcol;
        const int jl   = (jrow < NB) ? jrow : (NB - 1);
        const float* hj = hb + (size_t)jl * DIMH + kgrp * 8;
        f32x4 acc = {0.f, 0.f, 0.f, 0.f};
        #pragma unroll
        for (int ks = 0; ks < 4; ++ks) {
            float4 ra = *(const float4*)(hj + ks * 32);
            float4 rb = *(const float4*)(hj + ks * 32 + 4);
            u32x4 bh = { pack_hi2(ra.x, ra.y), pack_hi2(ra.z, ra.w),
                         pack_hi2(rb.x, rb.y), pack_hi2(rb.z, rb.w) };
            u32x4 bl = { pack_hi2(ra.x - hi_of(ra.x), ra.y - hi_of(ra.y)),
                         pack_hi2(ra.z - hi_of(ra.z), ra.w - hi_of(ra.w)),
                         pack_hi2(rb.x - hi_of(rb.x), rb.y - hi_of(rb.y)),
                         pack_hi2(rb.z - hi_of(rb.z), rb.w - hi_of(rb.w)) };
            short8v Bh = __builtin_bit_cast(short8v, bh);
            short8v Bl = __builtin_bit_cast(short8v, bl);
            acc = __builtin_amdgcn_mfma_f32_16x16x32_bf16(Ahi[ks], Bh, acc, 0, 0, 0);
            acc = __builtin_amdgcn_mfma_f32_16x16x32_bf16(Alo[ks], Bh, acc, 0, 0, 0);
            acc = __builtin_amdgcn_mfma_f32_16x16x32_bf16(Ahi[ks], Bl, acc, 0, 0, 0);
        }
        int kk = adj[(size_t)(b * NB + i0 + kgrp) * NB + jl];
        int mm = mask[b * NB + jl];
        float ev = (kk == 1) ? acc[0] : (kk == 2) ? acc[1] :
                   (kk == 3) ? acc[2] : (kk == 4) ? acc[3] : 0.0f;
        ev = (ev >= 0.0f) ? ev : 0.2f * ev;
        float x = ev * 0.1f;
        if (mm == 0)     x = -INFINITY;
        if (jrow >= NB)  x = -INFINITY;
        xs[kgrp][jrow] = x;
    }
    __syncthreads();

    float x0 = xs[r][lane];
    float x1 = xs[r][lane + 64];
    float x2 = xs[r][lane + 128];
    float x3 = (lane < 16) ? xs[r][192 + lane] : -INFINITY;

    float mx  = wmax_dpp(fmaxf(fmaxf(x0, x1), fmaxf(x2, x3)));
    float tau = mx - 1.0f;
    #define P10(v, tt) ({ float z_ = fmaxf((v) - (tt), 0.f); float z2 = z_*z_; float z4 = z2*z2; float z8 = z4*z4; z8*z2; })
    float s0 = P10(x0, tau) + P10(x1, tau) + P10(x2, tau) + P10(x3, tau);
    float f_lo = wsum_dpp(s0) - 1.0f;
    float dm   = (mx - 0.58870401f) - tau;

    for (int itn = 0; itn < NITER; ++itn) {
        dm *= 0.5f;
        float tm = tau + dm;
        float s = P10(x0, tm) + P10(x1, tm) + P10(x2, tm) + P10(x3, tm);
        float fm = wsum_dpp(s) - 1.0f;
        if (fm * f_lo >= 0.0f) tau = tm;
    }
    float p0 = P10(x0, tau);
    float p1 = P10(x1, tau);
    float p2 = P10(x2, tau);
    float p3 = P10(x3, tau);
    #undef P10
    float sinv = 1.0f / wsum_dpp(p0 + p1 + p2 + p3);
    xs[r][lane]       = p0 * sinv;
    xs[r][lane + 64]  = p1 * sinv;
    xs[r][lane + 128] = p2 * sinv;
    if (lane < 16) xs[r][192 + lane] = p3 * sinv;
    __syncthreads();

    const int J0 = r * 50;
    float pj0 = (lane < 50) ? xs[0][J0 + lane] : 0.f;
    float pj1 = (lane < 50) ? xs[1][J0 + lane] : 0.f;
    float pj2 = (lane < 50) ? xs[2][J0 + lane] : 0.f;
    float pj3 = (lane < 50) ? xs[3][J0 + lane] : 0.f;
    float2 ov0 = {0.f,0.f}, ov1 = {0.f,0.f}, ov2 = {0.f,0.f}, ov3 = {0.f,0.f};
    {
        const float* hjb = hb + (size_t)J0 * DIMH + d2;
        #pragma unroll 5
        for (int jj = 0; jj < 50; ++jj) {
            float2 hv = *(const float2*)(hjb + jj * DIMH);
            float c0 = rdlane(pj0, jj), c1 = rdlane(pj1, jj);
            float c2 = rdlane(pj2, jj), c3 = rdlane(pj3, jj);
            ov0.x = fmaf(c0, hv.x, ov0.x); ov0.y = fmaf(c0, hv.y, ov0.y);
            ov1.x = fmaf(c1, hv.x, ov1.x); ov1.y = fmaf(c1, hv.y, ov1.y);
            ov2.x = fmaf(c2, hv.x, ov2.x); ov2.y = fmaf(c2, hv.y, ov2.y);
            ov3.x = fmaf(c3, hv.x, ov3.x); ov3.y = fmaf(c3, hv.y, ov3.y);
        }
    }
    *(float2*)&scrf[(r * 4 + 0) * DIMH + d2] = ov0;
    *(float2*)&scrf[(r * 4 + 1) * DIMH + d2] = ov1;
    *(float2*)&scrf[(r * 4 + 2) * DIMH + d2] = ov2;
    *(float2*)&scrf[(r * 4 + 3) * DIMH + d2] = ov3;
    __syncthreads();
    float2 o;
    {
        float2 q0 = *(const float2*)&scrf[(0 * 4 + r) * DIMH + d2];
        float2 q1 = *(const float2*)&scrf[(1 * 4 + r) * DIMH + d2];
        float2 q2 = *(const float2*)&scrf[(2 * 4 + r) * DIMH + d2];
        float2 q3 = *(const float2*)&scrf[(3 * 4 + r) * DIMH + d2];
        o.x = (q0.x + q1.x) + (q2.x + q3.x);
        o.y = (q0.y + q1.y) + (q2.y + q3.y);
    }
    *(float2*)&cop[r][DIMH + d2] = o;
    __syncthreads();

    float2 ov = *(const float2*)&cop[r][DIMH + d2];
    float2 gres;

    if constexpr (MODE >= 1) {
        float hx = cop[r][d2], hy = cop[r][d2 + 1];
        cbf[0][r][lane]      = pack_hi2(hx, hy);
        cbf[1][r][lane]      = pack_hi2(hx - hi_of(hx), hy - hi_of(hy));
        cbf[0][r][64 + lane] = pack_hi2(ov.x, ov.y);
        cbf[1][r][64 + lane] = pack_hi2(ov.x - hi_of(ov.x), ov.y - hi_of(ov.y));
        __syncthreads();
        f32x4 ga0 = {0.f,0.f,0.f,0.f}, ga1 = {0.f,0.f,0.f,0.f};
        const int arow = lane & 3;
        const int au   = (lane >> 4) * 4;
        #pragma unroll
        for (int ks = 0; ks < 8; ++ks) {
            short8v Ah = __builtin_bit_cast(short8v, *(const u32x4*)&cbf[0][arow][ks * 16 + au]);
            short8v Al = __builtin_bit_cast(short8v, *(const u32x4*)&cbf[1][arow][ks * 16 + au]);
            const unsigned bi0 = (((2 * r) * 8 + ks) * 64 + lane) * 4;
            const unsigned bi1 = (((2 * r + 1) * 8 + ks) * 64 + lane) * 4;
            short8v Bh0 = __builtin_bit_cast(short8v, *(const u32x4*)&wf[bi0]);
            short8v Bl0 = __builtin_bit_cast(short8v, *(const u32x4*)&wf[WF_U32 / 2 + bi0]);
            short8v Bh1 = __builtin_bit_cast(short8v, *(const u32x4*)&wf[bi1]);
            short8v Bl1 = __builtin_bit_cast(short8v, *(const u32x4*)&wf[WF_U32 / 2 + bi1]);
            ga0 = __builtin_amdgcn_mfma_f32_16x16x32_bf16(Ah, Bh0, ga0, 0, 0, 0);
            ga0 = __builtin_amdgcn_mfma_f32_16x16x32_bf16(Al, Bh0, ga0, 0, 0, 0);
            ga0 = __builtin_amdgcn_mfma_f32_16x16x32_bf16(Ah, Bl0, ga0, 0, 0, 0);
            ga1 = __builtin_amdgcn_mfma_f32_16x16x32_bf16(Ah, Bh1, ga1, 0, 0, 0);
            ga1 = __builtin_amdgcn_mfma_f32_16x16x32_bf16(Al, Bh1, ga1, 0, 0, 0);
            ga1 = __builtin_amdgcn_mfma_f32_16x16x32_bf16(Ah, Bl1, ga1, 0, 0, 0);
        }
        if (lane < 16) {
            #pragma unroll
            for (int m = 0; m < 4; ++m) {
                xs[m][(2 * r) * 16 + lane]     = ga0[m];
                xs[m][(2 * r + 1) * 16 + lane] = ga1[m];
            }
        }
        __syncthreads();
        gres.x = xs[r][d2];
        gres.y = xs[r][d2 + 1];
    } else {
        float cv0 = cop[0][64 * r + lane];
        float cv1 = cop[1][64 * r + lane];
        float cv2 = cop[2][64 * r + lane];
        float cv3 = cop[3][64 * r + lane];
        float2 gv0 = {0.f,0.f}, gv1 = {0.f,0.f}, gv2 = {0.f,0.f}, gv3 = {0.f,0.f};
        const float* wb = W + (size_t)(64 * r) * DIMH + d2;
        #pragma unroll 8
        for (int ee = 0; ee < 64; ++ee) {
            float2 wv = *(const float2*)(wb + ee * DIMH);
            float c0 = rdlane(cv0, ee), c1 = rdlane(cv1, ee);
            float c2 = rdlane(cv2, ee), c3 = rdlane(cv3, ee);
            gv0.x = fmaf(c0, wv.x, gv0.x); gv0.y = fmaf(c0, wv.y, gv0.y);
            gv1.x = fmaf(c1, wv.x, gv1.x); gv1.y = fmaf(c1, wv.y, gv1.y);
            gv2.x = fmaf(c2, wv.x, gv2.x); gv2.y = fmaf(c2, wv.y, gv2.y);
            gv3.x = fmaf(c3, wv.x, gv3.x); gv3.y = fmaf(c3, wv.y, gv3.y);
        }
        *(float2*)&scrf[(r * 4 + 0) * DIMH + d2] = gv0;
        *(float2*)&scrf[(r * 4 + 1) * DIMH + d2] = gv1;
        *(float2*)&scrf[(r * 4 + 2) * DIMH + d2] = gv2;
        *(float2*)&scrf[(r * 4 + 3) * DIMH + d2] = gv3;
        __syncthreads();
        float2 q0 = *(const float2*)&scrf[(0 * 4 + r) * DIMH + d2];
        float2 q1 = *(const float2*)&scrf[(1 * 4 + r) * DIMH + d2];
        float2 q2 = *(const float2*)&scrf[(2 * 4 + r) * DIMH + d2];
        float2 q3 = *(const float2*)&scrf[(3 * 4 + r) * DIMH + d2];
        gres.x = (q0.x + q1.x) + (q2.x + q3.x);
        gres.y = (q0.y + q1.y) + (q2.y + q3.y);
    }

    {
        float2 bv = *(const float2*)(bias + d2);
        float gx = gres.x + bv.x;
        float gy = gres.y + bv.y;
        float sgx = 1.0f / (1.0f + __expf(-gx));
        float sgy = 1.0f / (1.0f + __expf(-gy));
        float2 hf = *(const float2*)&cop[r][d2];
        const size_t gi = (size_t)(b * NB + i0 + r) * DIMH;
        float2 res;
        res.x = sgx * ov.x + (1.0f - sgx) * hf.x;
        res.y = sgy * ov.y + (1.0f - sgy) * hf.y;
        *(float2*)(out + gi + d2) = res;
    }
}

extern "C" void kernel_launch(void* const* d_in, const int* in_sizes, int n_in,
                              void* d_out, int out_size, void* d_ws, size_t ws_size,
                              hipStream_t stream)
{
    const float* hidden = (const float*)d_in[0];
    const int*   adj    = (const int*)d_in[1];
    const int*   mask   = (const int*)d_in[2];
    const float* a0     = (const float*)d_in[3];
    const float* a1     = (const float*)d_in[4];
    const float* a2     = (const float*)d_in[5];
    const float* a3     = (const float*)d_in[6];
    const float* W      = (const float*)d_in[7];
    const float* bias   = (const float*)d_in[8];
    float* out = (float*)d_out;

    const int B = in_sizes[0] / (NB * DIMH);   // 256

    const size_t hsN = (size_t)B * NB * 64;
    const size_t htN = (size_t)B * DIMH * KJ2;
    const size_t fullU32 = (size_t)WF_U32 + 2 * hsN + 2 * htN;

    if (ws_size >= fullU32 * sizeof(unsigned)) {
        unsigned* wf    = (unsigned*)d_ws;
        unsigned* hs_hi = wf + WF_U32;
        unsigned* hs_lo = hs_hi + hsN;
        unsigned* ht_hi = hs_lo + hsN;
        unsigned* ht_lo = ht_hi + htN;
        conv_w<<<64, 64, 0, stream>>>(W, wf);
        conv_hs<<<(unsigned)(hsN / 256), 256, 0, stream>>>(hidden, hs_hi, hs_lo);
        conv_ht<<<B * 28, 256, 0, stream>>>(hidden, ht_hi, ht_lo);
        dim3 grid8(B * (NB / ROWS8));
        la_fused8<<<grid8, TPB8, 0, stream>>>(hidden, adj, mask, a0, a1, a2, a3,
                                              bias, wf, hs_hi, hs_lo, ht_hi, ht_lo, out);
    } else if (ws_size >= (size_t)WF_U32 * sizeof(unsigned)) {
        unsigned* wf = (unsigned*)d_ws;
        conv_w<<<64, 64, 0, stream>>>(W, wf);
        dim3 grid4(B * (NB / ROWS));
        la_fused<1><<<grid4, TPB, 0, stream>>>(hidden, adj, mask, a0, a1, a2, a3,
                                               W, bias, wf, out);
    } else {
        dim3 grid4(B * (NB / ROWS));
        la_fused<0><<<grid4, TPB, 0, stream>>>(hidden, adj, mask, a0, a1, a2, a3,
                                               W, bias, nullptr, out);
    }
}

// Round 14
// 200.739 us; speedup vs baseline: 1.8654x; 1.3837x over previous
//
#include <hip/hip_runtime.h>
#include <math.h>

#define NB    200
#define DIMH  128
#define TPB8  512
#define ROWS8 8
#define NITER 12   // tau err 0.411*2^-12 ~ 1e-4 -> p err ~1e-3, threshold 8.5e-2
#define NJT   13   // j-tiles of 16 covering 208
#define KJ2   112  // padded j-pairs for PV (224 j's)

typedef __attribute__((ext_vector_type(8))) short  short8v;
typedef __attribute__((ext_vector_type(4))) float  f32x4;
typedef __attribute__((ext_vector_type(4))) unsigned u32x4;

#define WF_U32 32768   // W-frag table: 8nt*8ks*64lane*4 u32 (hi) + same (lo)

__device__ __forceinline__ unsigned pack_hi2(float a, float b){
    return (__builtin_bit_cast(unsigned, a) >> 16) |
           (__builtin_bit_cast(unsigned, b) & 0xFFFF0000u);
}
__device__ __forceinline__ float hi_of(float x){
    return __builtin_bit_cast(float, __builtin_bit_cast(unsigned, x) & 0xFFFF0000u);
}
__device__ __forceinline__ float rdlane(float v, int l){
    return __builtin_bit_cast(float,
        __builtin_amdgcn_readlane(__builtin_bit_cast(int, v), l));
}
__device__ __forceinline__ float wsum_dpp(float v){
#define DPP_ADD(ctrl, rmask)                                                     \
    {                                                                            \
        int t_ = __builtin_amdgcn_update_dpp(0, __builtin_bit_cast(int, v),      \
                                             ctrl, rmask, 0xf, false);           \
        v += __builtin_bit_cast(float, t_);                                      \
    }
    DPP_ADD(0x111, 0xf)
    DPP_ADD(0x112, 0xf)
    DPP_ADD(0x114, 0xf)
    DPP_ADD(0x118, 0xf)
    DPP_ADD(0x142, 0xa)
    DPP_ADD(0x143, 0xc)
#undef DPP_ADD
    return rdlane(v, 63);
}
__device__ __forceinline__ float wmax_dpp(float v){
#define DPP_MAX(ctrl, rmask)                                                     \
    {                                                                            \
        int t_ = __builtin_amdgcn_update_dpp(__builtin_bit_cast(int, v),         \
                                             __builtin_bit_cast(int, v),         \
                                             ctrl, rmask, 0xf, false);           \
        v = fmaxf(v, __builtin_bit_cast(float, t_));                             \
    }
    DPP_MAX(0x111, 0xf)
    DPP_MAX(0x112, 0xf)
    DPP_MAX(0x114, 0xf)
    DPP_MAX(0x118, 0xf)
    DPP_MAX(0x142, 0xa)
    DPP_MAX(0x143, 0xc)
#undef DPP_MAX
    return rdlane(v, 63);
}

// One-time W -> bf16 hi/lo fragment table (gate MFMA B layout). Validated r10/r11.
__global__ __launch_bounds__(64) void conv_w(const float* __restrict__ W,
                                             unsigned* __restrict__ wf){
    const int lane = threadIdx.x;
    const int ks = blockIdx.x & 7, nt = blockIdx.x >> 3;
    const int krow = ks * 32 + (lane >> 4) * 8;
    const int col  = nt * 16 + (lane & 15);
    unsigned hi[4], lo[4];
    #pragma unroll
    for (int q2 = 0; q2 < 4; ++q2) {
        float v0 = W[(size_t)(krow + 2 * q2) * DIMH + col];
        float v1 = W[(size_t)(krow + 2 * q2 + 1) * DIMH + col];
        hi[q2] = pack_hi2(v0, v1);
        lo[q2] = pack_hi2(v0 - hi_of(v0), v1 - hi_of(v1));
    }
    const unsigned base = (blockIdx.x * 64 + lane) * 4;
    *(u32x4*)&wf[base]              = (u32x4){hi[0], hi[1], hi[2], hi[3]};
    *(u32x4*)&wf[WF_U32 / 2 + base] = (u32x4){lo[0], lo[1], lo[2], lo[3]};
}

// hidden -> hs[b][j][d2] bf16 hi/lo (score B layout). Validated r11.
__global__ __launch_bounds__(256) void conv_hs(const float* __restrict__ hidden,
                                               unsigned* __restrict__ hs_hi,
                                               unsigned* __restrict__ hs_lo){
    size_t gid = (size_t)blockIdx.x * 256 + threadIdx.x;
    float2 h2 = *(const float2*)(hidden + gid * 2);
    hs_hi[gid] = pack_hi2(h2.x, h2.y);
    hs_lo[gid] = pack_hi2(h2.x - hi_of(h2.x), h2.y - hi_of(h2.y));
}

// hidden -> ht[b][d][j2] bf16 (transposed, padded to 224 j: PV B layout).
// r14: hi only — PV drops the Ph*Blo term (error ~2e-3 rel, threshold headroom 5x).
__global__ __launch_bounds__(256) void conv_ht(const float* __restrict__ hidden,
                                               unsigned* __restrict__ ht_hi){
    __shared__ float tile[32][33];
    const int bid = blockIdx.x;
    const int b  = bid / 28;
    const int rem = bid % 28;
    const int jt = rem >> 2, dt = rem & 3;
    const int j0 = jt * 32, d0 = dt * 32;
    const int tt = threadIdx.x;
    #pragma unroll
    for (int rr = 0; rr < 4; ++rr) {
        int j = j0 + (tt >> 5) + rr * 8;
        int d = d0 + (tt & 31);
        tile[(tt >> 5) + rr * 8][tt & 31] =
            (j < NB) ? hidden[((size_t)b * NB + j) * DIMH + d] : 0.0f;
    }
    __syncthreads();
    #pragma unroll
    for (int it = 0; it < 2; ++it) {
        int j2 = it * 8 + (tt & 7);
        int dl = tt >> 3;
        float v0 = tile[2 * j2][dl];
        float v1 = tile[2 * j2 + 1][dl];
        size_t o = ((size_t)b * DIMH + d0 + dl) * KJ2 + (j0 >> 1) + j2;
        ht_hi[o] = pack_hi2(v0, v1);
    }
}

// r14: 8 rows/block + XCD swizzle (batch-local L2) + dual-tile score waves
// (hs read once) + bf16-only H/W operands in PV/gate (score keeps 3-term).
__global__ __launch_bounds__(TPB8, 4) void la_fused8(
    const float* __restrict__ hidden,
    const int*   __restrict__ adj,
    const int*   __restrict__ mask,
    const float* __restrict__ a0, const float* __restrict__ a1,
    const float* __restrict__ a2, const float* __restrict__ a3,
    const float* __restrict__ bias,
    const unsigned* __restrict__ wf,
    const unsigned* __restrict__ hs_hi, const unsigned* __restrict__ hs_lo,
    const unsigned* __restrict__ ht_hi,
    float* __restrict__ out)
{
    __shared__ unsigned hab[2][32][68];    // ha bf16x2 [hi/lo][rk=8rows x 4k][d2]
    __shared__ float xs[ROWS8][208];       // scores -> p; later gate-output buffer
    __shared__ float cop[ROWS8][256];      // [0:128)=h_i, [128:256)=o
    __shared__ unsigned pbf[2 * ROWS8 * 116]; // P bf16 hi/lo
    __shared__ unsigned cbf[2][ROWS8][132];   // gate A rows bf16x2

    const int t    = threadIdx.x;
    const int lane = t & 63;
    const int r    = t >> 6;               // wave id 0..7 == row owned
    const int d2   = 2 * lane;
    // XCD swizzle: grid 6400 = 8 x 800; 800 % 25 == 0 -> all 25 blocks of a
    // batch get blockIdx.x congruent mod 8 -> same XCD L2 holds the batch set.
    const int bid  = (blockIdx.x & 7) * ((int)gridDim.x >> 3) + (blockIdx.x >> 3);
    const int b    = bid / (NB / ROWS8);   // NB/ROWS8 = 25
    const int i0   = (bid % (NB / ROWS8)) * ROWS8;

    const float* hb = hidden + (size_t)b * NB * DIMH;

    // ---- stage h_i rows (cop) and bf16 hi/lo ha table (coalesced) ----
    for (int idx = t; idx < ROWS8 * DIMH; idx += TPB8) {
        int rr = idx >> 7, d = idx & 127;
        cop[rr][d] = hb[(i0 + rr) * DIMH + d];
    }
    for (int s = t; s < 32 * 64; s += TPB8) {
        int rk = s >> 6, dd = s & 63;
        int rr = rk >> 2, k = rk & 3;
        int d  = dd * 2;
        const float* ap = (k == 0) ? a0 : (k == 1) ? a1 : (k == 2) ? a2 : a3;
        float h0 = hb[(i0 + rr) * DIMH + d];
        float h1 = hb[(i0 + rr) * DIMH + d + 1];
        float q0 = h0 * ap[d];
        float q1 = h1 * ap[d + 1];
        hab[0][rk][dd] = pack_hi2(q0, q1);
        hab[1][rk][dd] = pack_hi2(q0 - hi_of(q0), q1 - hi_of(q1));
    }
    __syncthreads();                                   // A

    // ---- A-fragments for BOTH 16-row tiles (dual-tile score waves) ----
    short8v Ahi[2][4], Alo[2][4];
    {
        const int au = (lane >> 4) * 4;
        #pragma unroll
        for (int tl = 0; tl < 2; ++tl) {
            const int arow = tl * 16 + (lane & 15);
            #pragma unroll
            for (int ks = 0; ks < 4; ++ks) {
                Ahi[tl][ks] = __builtin_bit_cast(short8v, *(const u32x4*)&hab[0][arow][ks * 16 + au]);
                Alo[tl][ks] = __builtin_bit_cast(short8v, *(const u32x4*)&hab[1][arow][ks * 16 + au]);
            }
        }
    }

    // ---- score via MFMA: wave r does jt = r, r+8 (<13); B loaded ONCE per jt ----
    const int jcol = lane & 15;
    const int kgrp = lane >> 4;
    for (int jt = r; jt < NJT; jt += 8) {
        const int jrow = jt * 16 + jcol;
        const int jl   = (jrow < NB) ? jrow : (NB - 1);
        f32x4 acc0 = {0.f, 0.f, 0.f, 0.f};
        f32x4 acc1 = {0.f, 0.f, 0.f, 0.f};
        const unsigned* bhp = hs_hi + ((size_t)(b * NB + jl) << 6) + kgrp * 4;
        const unsigned* blp = hs_lo + ((size_t)(b * NB + jl) << 6) + kgrp * 4;
        #pragma unroll
        for (int ks = 0; ks < 4; ++ks) {
            short8v Bh = __builtin_bit_cast(short8v, *(const u32x4*)(bhp + ks * 16));
            short8v Bl = __builtin_bit_cast(short8v, *(const u32x4*)(blp + ks * 16));
            acc0 = __builtin_amdgcn_mfma_f32_16x16x32_bf16(Ahi[0][ks], Bh, acc0, 0, 0, 0);
            acc0 = __builtin_amdgcn_mfma_f32_16x16x32_bf16(Alo[0][ks], Bh, acc0, 0, 0, 0);
            acc0 = __builtin_amdgcn_mfma_f32_16x16x32_bf16(Ahi[0][ks], Bl, acc0, 0, 0, 0);
            acc1 = __builtin_amdgcn_mfma_f32_16x16x32_bf16(Ahi[1][ks], Bh, acc1, 0, 0, 0);
            acc1 = __builtin_amdgcn_mfma_f32_16x16x32_bf16(Alo[1][ks], Bh, acc1, 0, 0, 0);
            acc1 = __builtin_amdgcn_mfma_f32_16x16x32_bf16(Ahi[1][ks], Bl, acc1, 0, 0, 0);
        }
        const int mm  = mask[b * NB + jl];
        const int kk0 = adj[(size_t)(b * NB + i0 + kgrp) * NB + jl];
        const int kk1 = adj[(size_t)(b * NB + i0 + 4 + kgrp) * NB + jl];
        float ev0 = (kk0 == 1) ? acc0[0] : (kk0 == 2) ? acc0[1] :
                    (kk0 == 3) ? acc0[2] : (kk0 == 4) ? acc0[3] : 0.0f;
        float ev1 = (kk1 == 1) ? acc1[0] : (kk1 == 2) ? acc1[1] :
                    (kk1 == 3) ? acc1[2] : (kk1 == 4) ? acc1[3] : 0.0f;
        ev0 = (ev0 >= 0.0f) ? ev0 : 0.2f * ev0;        // leaky relu 0.2
        ev1 = (ev1 >= 0.0f) ? ev1 : 0.2f * ev1;
        float xv0 = ev0 * 0.1f;                        // * (alpha-1)
        float xv1 = ev1 * 0.1f;
        if (mm == 0 || jrow >= NB) { xv0 = -INFINITY; xv1 = -INFINITY; }
        xs[kgrp][jrow]     = xv0;
        xs[4 + kgrp][jrow] = xv1;
    }
    __syncthreads();                                   // B

    // ---- entmax bisection: wave r owns row i0+r ----
    float x0 = xs[r][lane];
    float x1 = xs[r][lane + 64];
    float x2 = xs[r][lane + 128];
    float x3 = (lane < 16) ? xs[r][192 + lane] : -INFINITY;

    float mx  = wmax_dpp(fmaxf(fmaxf(x0, x1), fmaxf(x2, x3)));
    float tau = mx - 1.0f;
    #define P10(v, tt) ({ float z_ = fmaxf((v) - (tt), 0.f); float z2 = z_*z_; float z4 = z2*z2; float z8 = z4*z4; z8*z2; })
    float s0 = P10(x0, tau) + P10(x1, tau) + P10(x2, tau) + P10(x3, tau);
    float f_lo = wsum_dpp(s0) - 1.0f;                  // captured once (matches ref)
    float dm   = (mx - 0.58870401f) - tau;             // (1/200)^0.1

    for (int itn = 0; itn < NITER; ++itn) {
        dm *= 0.5f;
        float tm = tau + dm;
        float s = P10(x0, tm) + P10(x1, tm) + P10(x2, tm) + P10(x3, tm);
        float fm = wsum_dpp(s) - 1.0f;
        if (fm * f_lo >= 0.0f) tau = tm;
    }
    float p0 = P10(x0, tau);
    float p1 = P10(x1, tau);
    float p2 = P10(x2, tau);
    float p3 = P10(x3, tau);
    #undef P10
    float sinv = 1.0f / wsum_dpp(p0 + p1 + p2 + p3);   // ensure_sum_one
    xs[r][lane]       = p0 * sinv;                     // wave-local write-back
    xs[r][lane + 64]  = p1 * sinv;
    xs[r][lane + 128] = p2 * sinv;
    if (lane < 16) xs[r][192 + lane] = p3 * sinv;

    // ---- pbf row r built wave-locally (no barrier: own row) ----
    for (int k2 = lane; k2 < KJ2; k2 += 64) {
        int j = 2 * k2;
        float v0 = (j < 208)     ? xs[r][j]     : 0.0f;
        float v1 = (j + 1 < 208) ? xs[r][j + 1] : 0.0f;
        pbf[r * 116 + k2]                = pack_hi2(v0, v1);
        pbf[ROWS8 * 116 + r * 116 + k2]  = pack_hi2(v0 - hi_of(v0), v1 - hi_of(v1));
    }
    __syncthreads();                                   // C: all pbf rows visible

    // ---- PV via MFMA: wave r does n-tile r; P hi/lo x H bf16 (2 MFMA/ks) ----
    {
        f32x4 av = {0.f, 0.f, 0.f, 0.f};
        const int prow = lane & 7;
        const int au   = (lane >> 4) * 4;
        const int dc   = 16 * r + (lane & 15);
        const size_t base = ((size_t)(b * DIMH + dc)) * KJ2 + au;
        #pragma unroll
        for (int ks = 0; ks < 7; ++ks) {
            short8v Ph = __builtin_bit_cast(short8v, *(const u32x4*)&pbf[prow * 116 + ks * 16 + au]);
            short8v Pl = __builtin_bit_cast(short8v, *(const u32x4*)&pbf[ROWS8 * 116 + prow * 116 + ks * 16 + au]);
            short8v Bh = __builtin_bit_cast(short8v, *(const u32x4*)(ht_hi + base + ks * 16));
            av = __builtin_amdgcn_mfma_f32_16x16x32_bf16(Ph, Bh, av, 0, 0, 0);
            av = __builtin_amdgcn_mfma_f32_16x16x32_bf16(Pl, Bh, av, 0, 0, 0);
        }
        if (lane < 32) {
            const int rbase = (lane >> 4) * 4;
            #pragma unroll
            for (int q = 0; q < 4; ++q)
                cop[rbase + q][DIMH + 16 * r + (lane & 15)] = av[q];
        }
    }
    __syncthreads();                                   // E: o rows complete

    float2 ovv = *(const float2*)&cop[r][DIMH + d2];

    // ---- gate via MFMA: C hi/lo x W bf16 (2 MFMA/ks); wave r does n-tile r ----
    {
        float hx = cop[r][d2], hy = cop[r][d2 + 1];
        cbf[0][r][lane]      = pack_hi2(hx, hy);
        cbf[1][r][lane]      = pack_hi2(hx - hi_of(hx), hy - hi_of(hy));
        cbf[0][r][64 + lane] = pack_hi2(ovv.x, ovv.y);
        cbf[1][r][64 + lane] = pack_hi2(ovv.x - hi_of(ovv.x), ovv.y - hi_of(ovv.y));
    }
    __syncthreads();                                   // F

    {
        f32x4 ga = {0.f, 0.f, 0.f, 0.f};
        const int arow = lane & 7;
        const int au   = (lane >> 4) * 4;
        #pragma unroll
        for (int ks = 0; ks < 8; ++ks) {
            short8v Ah = __builtin_bit_cast(short8v, *(const u32x4*)&cbf[0][arow][ks * 16 + au]);
            short8v Al = __builtin_bit_cast(short8v, *(const u32x4*)&cbf[1][arow][ks * 16 + au]);
            const unsigned bi = ((r * 8 + ks) * 64 + lane) * 4;
            short8v Bh = __builtin_bit_cast(short8v, *(const u32x4*)&wf[bi]);
            ga = __builtin_amdgcn_mfma_f32_16x16x32_bf16(Ah, Bh, ga, 0, 0, 0);
            ga = __builtin_amdgcn_mfma_f32_16x16x32_bf16(Al, Bh, ga, 0, 0, 0);
        }
        if (lane < 32) {                               // rows 0..7 once (xs = gbuf)
            const int rbase = (lane >> 4) * 4;
            #pragma unroll
            for (int q = 0; q < 4; ++q)
                xs[rbase + q][16 * r + (lane & 15)] = ga[q];
        }
    }
    __syncthreads();                                   // G

    // ---- final: bias, sigmoid, mix, store ----
    {
        float2 bv = *(const float2*)(bias + d2);
        float gx = xs[r][d2]     + bv.x;
        float gy = xs[r][d2 + 1] + bv.y;
        float sgx = 1.0f / (1.0f + __expf(-gx));
        float sgy = 1.0f / (1.0f + __expf(-gy));
        float2 hf = *(const float2*)&cop[r][d2];
        const size_t gi = (size_t)(b * NB + i0 + r) * DIMH;
        float2 res;
        res.x = sgx * ovv.x + (1.0f - sgx) * hf.x;
        res.y = sgy * ovv.y + (1.0f - sgy) * hf.y;
        *(float2*)(out + gi + d2) = res;
    }
}

// ---------------- fallback 4-row kernel (modes 1/0), r11-validated structure ----------------
#define ROWS  4
#define TPB   256
template<int MODE>
__global__ __launch_bounds__(TPB, 4) void la_fused(
    const float* __restrict__ hidden,
    const int*   __restrict__ adj,
    const int*   __restrict__ mask,
    const float* __restrict__ a0, const float* __restrict__ a1,
    const float* __restrict__ a2, const float* __restrict__ a3,
    const float* __restrict__ W,  const float* __restrict__ bias,
    const unsigned* __restrict__ wf,
    float* __restrict__ out)
{
    __shared__ unsigned hab[2][16][68];
    __shared__ float xs[ROWS][208];
    __shared__ float cop[ROWS][256];
    __shared__ float scrf[ROWS * ROWS * DIMH];
    __shared__ unsigned cbf[2][ROWS][132];

    const int t    = threadIdx.x;
    const int lane = t & 63;
    const int r    = t >> 6;
    const int d2   = 2 * lane;
    const int bid  = blockIdx.x;
    const int b    = bid / (NB / ROWS);
    const int i0   = (bid % (NB / ROWS)) * ROWS;

    const float* hb = hidden + (size_t)b * NB * DIMH;

    for (int idx = t; idx < ROWS * DIMH; idx += TPB) {
        int rr = idx >> 7, d = idx & 127;
        cop[rr][d] = hb[(i0 + rr) * DIMH + d];
    }
    for (int s = t; s < 16 * 64; s += TPB) {
        int rk = s >> 6, dd = s & 63;
        int rr = rk >> 2, k = rk & 3;
        int d  = dd * 2;
        const float* ap = (k == 0) ? a0 : (k == 1) ? a1 : (k == 2) ? a2 : a3;
        float h0 = hb[(i0 + rr) * DIMH + d];
        float h1 = hb[(i0 + rr) * DIMH + d + 1];
        float q0 = h0 * ap[d];
        float q1 = h1 * ap[d + 1];
        hab[0][rk][dd] = pack_hi2(q0, q1);
        hab[1][rk][dd] = pack_hi2(q0 - hi_of(q0), q1 - hi_of(q1));
    }
    __syncthreads();

    short8v Ahi[4], Alo[4];
    {
        const int arow = lane & 15;
        const int au   = (lane >> 4) * 4;
        #pragma unroll
        for (int ks = 0; ks < 4; ++ks) {
            Ahi[ks] = __builtin_bit_cast(short8v, *(const u32x4*)&hab[0][arow][ks * 16 + au]);
            Alo[ks] = __builtin_bit_cast(short8v, *(const u32x4*)&hab[1][arow][ks * 16 + au]);
        }
    }

    const int jcol = lane & 15;
    const int kgrp = lane >> 4;
    for (int jt = r; jt < NJT; jt += 4) {
        const int jrow = jt * 16 + jcol;
        const int jl   = (jrow < NB) ? jrow : (NB - 1);
        const float* hj = hb + (size_t)jl * DIMH + kgrp * 8;
        f32x4 acc = {0.f, 0.f, 0.f, 0.f};
        #pragma unroll
        for (int ks = 0; ks < 4; ++ks) {
            float4 ra = *(const float4*)(hj + ks * 32);
            float4 rb = *(const float4*)(hj + ks * 32 + 4);
            u32x4 bh = { pack_hi2(ra.x, ra.y), pack_hi2(ra.z, ra.w),
                         pack_hi2(rb.x, rb.y), pack_hi2(rb.z, rb.w) };
            u32x4 bl = { pack_hi2(ra.x - hi_of(ra.x), ra.y - hi_of(ra.y)),
                         pack_hi2(ra.z - hi_of(ra.z), ra.w - hi_of(ra.w)),
                         pack_hi2(rb.x - hi_of(rb.x), rb.y - hi_of(rb.y)),
                         pack_hi2(rb.z - hi_of(rb.z), rb.w - hi_of(rb.w)) };
            short8v Bh = __builtin_bit_cast(short8v, bh);
            short8v Bl = __builtin_bit_cast(short8v, bl);
            acc = __builtin_amdgcn_mfma_f32_16x16x32_bf16(Ahi[ks], Bh, acc, 0, 0, 0);
            acc = __builtin_amdgcn_mfma_f32_16x16x32_bf16(Alo[ks], Bh, acc, 0, 0, 0);
            acc = __builtin_amdgcn_mfma_f32_16x16x32_bf16(Ahi[ks], Bl, acc, 0, 0, 0);
        }
        int kk = adj[(size_t)(b * NB + i0 + kgrp) * NB + jl];
        int mm = mask[b * NB + jl];
        float ev = (kk == 1) ? acc[0] : (kk == 2) ? acc[1] :
                   (kk == 3) ? acc[2] : (kk == 4) ? acc[3] : 0.0f;
        ev = (ev >= 0.0f) ? ev : 0.2f * ev;
        float x = ev * 0.1f;
        if (mm == 0)     x = -INFINITY;
        if (jrow >= NB)  x = -INFINITY;
        xs[kgrp][jrow] = x;
    }
    __syncthreads();

    float x0 = xs[r][lane];
    float x1 = xs[r][lane + 64];
    float x2 = xs[r][lane + 128];
    float x3 = (lane < 16) ? xs[r][192 + lane] : -INFINITY;

    float mx  = wmax_dpp(fmaxf(fmaxf(x0, x1), fmaxf(x2, x3)));
    float tau = mx - 1.0f;
    #define P10(v, tt) ({ float z_ = fmaxf((v) - (tt), 0.f); float z2 = z_*z_; float z4 = z2*z2; float z8 = z4*z4; z8*z2; })
    float s0 = P10(x0, tau) + P10(x1, tau) + P10(x2, tau) + P10(x3, tau);
    float f_lo = wsum_dpp(s0) - 1.0f;
    float dm   = (mx - 0.58870401f) - tau;

    for (int itn = 0; itn < NITER; ++itn) {
        dm *= 0.5f;
        float tm = tau + dm;
        float s = P10(x0, tm) + P10(x1, tm) + P10(x2, tm) + P10(x3, tm);
        float fm = wsum_dpp(s) - 1.0f;
        if (fm * f_lo >= 0.0f) tau = tm;
    }
    float p0 = P10(x0, tau);
    float p1 = P10(x1, tau);
    float p2 = P10(x2, tau);
    float p3 = P10(x3, tau);
    #undef P10
    float sinv = 1.0f / wsum_dpp(p0 + p1 + p2 + p3);
    xs[r][lane]       = p0 * sinv;
    xs[r][lane + 64]  = p1 * sinv;
    xs[r][lane + 128] = p2 * sinv;
    if (lane < 16) xs[r][192 + lane] = p3 * sinv;
    __syncthreads();

    const int J0 = r * 50;
    float pj0 = (lane < 50) ? xs[0][J0 + lane] : 0.f;
    float pj1 = (lane < 50) ? xs[1][J0 + lane] : 0.f;
    float pj2 = (lane < 50) ? xs[2][J0 + lane] : 0.f;
    float pj3 = (lane < 50) ? xs[3][J0 + lane] : 0.f;
    float2 ov0 = {0.f,0.f}, ov1 = {0.f,0.f}, ov2 = {0.f,0.f}, ov3 = {0.f,0.f};
    {
        const float* hjb = hb + (size_t)J0 * DIMH + d2;
        #pragma unroll 5
        for (int jj = 0; jj < 50; ++jj) {
            float2 hv = *(const float2*)(hjb + jj * DIMH);
            float c0 = rdlane(pj0, jj), c1 = rdlane(pj1, jj);
            float c2 = rdlane(pj2, jj), c3 = rdlane(pj3, jj);
            ov0.x = fmaf(c0, hv.x, ov0.x); ov0.y = fmaf(c0, hv.y, ov0.y);
            ov1.x = fmaf(c1, hv.x, ov1.x); ov1.y = fmaf(c1, hv.y, ov1.y);
            ov2.x = fmaf(c2, hv.x, ov2.x); ov2.y = fmaf(c2, hv.y, ov2.y);
            ov3.x = fmaf(c3, hv.x, ov3.x); ov3.y = fmaf(c3, hv.y, ov3.y);
        }
    }
    *(float2*)&scrf[(r * 4 + 0) * DIMH + d2] = ov0;
    *(float2*)&scrf[(r * 4 + 1) * DIMH + d2] = ov1;
    *(float2*)&scrf[(r * 4 + 2) * DIMH + d2] = ov2;
    *(float2*)&scrf[(r * 4 + 3) * DIMH + d2] = ov3;
    __syncthreads();
    float2 o;
    {
        float2 q0 = *(const float2*)&scrf[(0 * 4 + r) * DIMH + d2];
        float2 q1 = *(const float2*)&scrf[(1 * 4 + r) * DIMH + d2];
        float2 q2 = *(const float2*)&scrf[(2 * 4 + r) * DIMH + d2];
        float2 q3 = *(const float2*)&scrf[(3 * 4 + r) * DIMH + d2];
        o.x = (q0.x + q1.x) + (q2.x + q3.x);
        o.y = (q0.y + q1.y) + (q2.y + q3.y);
    }
    *(float2*)&cop[r][DIMH + d2] = o;
    __syncthreads();

    float2 ov = *(const float2*)&cop[r][DIMH + d2];
    float2 gres;

    if constexpr (MODE >= 1) {
        float hx = cop[r][d2], hy = cop[r][d2 + 1];
        cbf[0][r][lane]      = pack_hi2(hx, hy);
        cbf[1][r][lane]      = pack_hi2(hx - hi_of(hx), hy - hi_of(hy));
        cbf[0][r][64 + lane] = pack_hi2(ov.x, ov.y);
        cbf[1][r][64 + lane] = pack_hi2(ov.x - hi_of(ov.x), ov.y - hi_of(ov.y));
        __syncthreads();
        f32x4 ga0 = {0.f,0.f,0.f,0.f}, ga1 = {0.f,0.f,0.f,0.f};
        const int arow = lane & 3;
        const int au   = (lane >> 4) * 4;
        #pragma unroll
        for (int ks = 0; ks < 8; ++ks) {
            short8v Ah = __builtin_bit_cast(short8v, *(const u32x4*)&cbf[0][arow][ks * 16 + au]);
            short8v Al = __builtin_bit_cast(short8v, *(const u32x4*)&cbf[1][arow][ks * 16 + au]);
            const unsigned bi0 = (((2 * r) * 8 + ks) * 64 + lane) * 4;
            const unsigned bi1 = (((2 * r + 1) * 8 + ks) * 64 + lane) * 4;
            short8v Bh0 = __builtin_bit_cast(short8v, *(const u32x4*)&wf[bi0]);
            short8v Bl0 = __builtin_bit_cast(short8v, *(const u32x4*)&wf[WF_U32 / 2 + bi0]);
            short8v Bh1 = __builtin_bit_cast(short8v, *(const u32x4*)&wf[bi1]);
            short8v Bl1 = __builtin_bit_cast(short8v, *(const u32x4*)&wf[WF_U32 / 2 + bi1]);
            ga0 = __builtin_amdgcn_mfma_f32_16x16x32_bf16(Ah, Bh0, ga0, 0, 0, 0);
            ga0 = __builtin_amdgcn_mfma_f32_16x16x32_bf16(Al, Bh0, ga0, 0, 0, 0);
            ga0 = __builtin_amdgcn_mfma_f32_16x16x32_bf16(Ah, Bl0, ga0, 0, 0, 0);
            ga1 = __builtin_amdgcn_mfma_f32_16x16x32_bf16(Ah, Bh1, ga1, 0, 0, 0);
            ga1 = __builtin_amdgcn_mfma_f32_16x16x32_bf16(Al, Bh1, ga1, 0, 0, 0);
            ga1 = __builtin_amdgcn_mfma_f32_16x16x32_bf16(Ah, Bl1, ga1, 0, 0, 0);
        }
        if (lane < 16) {
            #pragma unroll
            for (int m = 0; m < 4; ++m) {
                xs[m][(2 * r) * 16 + lane]     = ga0[m];
                xs[m][(2 * r + 1) * 16 + lane] = ga1[m];
            }
        }
        __syncthreads();
        gres.x = xs[r][d2];
        gres.y = xs[r][d2 + 1];
    } else {
        float cv0 = cop[0][64 * r + lane];
        float cv1 = cop[1][64 * r + lane];
        float cv2 = cop[2][64 * r + lane];
        float cv3 = cop[3][64 * r + lane];
        float2 gv0 = {0.f,0.f}, gv1 = {0.f,0.f}, gv2 = {0.f,0.f}, gv3 = {0.f,0.f};
        const float* wb = W + (size_t)(64 * r) * DIMH + d2;
        #pragma unroll 8
        for (int ee = 0; ee < 64; ++ee) {
            float2 wv = *(const float2*)(wb + ee * DIMH);
            float c0 = rdlane(cv0, ee), c1 = rdlane(cv1, ee);
            float c2 = rdlane(cv2, ee), c3 = rdlane(cv3, ee);
            gv0.x = fmaf(c0, wv.x, gv0.x); gv0.y = fmaf(c0, wv.y, gv0.y);
            gv1.x = fmaf(c1, wv.x, gv1.x); gv1.y = fmaf(c1, wv.y, gv1.y);
            gv2.x = fmaf(c2, wv.x, gv2.x); gv2.y = fmaf(c2, wv.y, gv2.y);
            gv3.x = fmaf(c3, wv.x, gv3.x); gv3.y = fmaf(c3, wv.y, gv3.y);
        }
        *(float2*)&scrf[(r * 4 + 0) * DIMH + d2] = gv0;
        *(float2*)&scrf[(r * 4 + 1) * DIMH + d2] = gv1;
        *(float2*)&scrf[(r * 4 + 2) * DIMH + d2] = gv2;
        *(float2*)&scrf[(r * 4 + 3) * DIMH + d2] = gv3;
        __syncthreads();
        float2 q0 = *(const float2*)&scrf[(0 * 4 + r) * DIMH + d2];
        float2 q1 = *(const float2*)&scrf[(1 * 4 + r) * DIMH + d2];
        float2 q2 = *(const float2*)&scrf[(2 * 4 + r) * DIMH + d2];
        float2 q3 = *(const float2*)&scrf[(3 * 4 + r) * DIMH + d2];
        gres.x = (q0.x + q1.x) + (q2.x + q3.x);
        gres.y = (q0.y + q1.y) + (q2.y + q3.y);
    }

    {
        float2 bv = *(const float2*)(bias + d2);
        float gx = gres.x + bv.x;
        float gy = gres.y + bv.y;
        float sgx = 1.0f / (1.0f + __expf(-gx));
        float sgy = 1.0f / (1.0f + __expf(-gy));
        float2 hf = *(const float2*)&cop[r][d2];
        const size_t gi = (size_t)(b * NB + i0 + r) * DIMH;
        float2 res;
        res.x = sgx * ov.x + (1.0f - sgx) * hf.x;
        res.y = sgy * ov.y + (1.0f - sgy) * hf.y;
        *(float2*)(out + gi + d2) = res;
    }
}

extern "C" void kernel_launch(void* const* d_in, const int* in_sizes, int n_in,
                              void* d_out, int out_size, void* d_ws, size_t ws_size,
                              hipStream_t stream)
{
    const float* hidden = (const float*)d_in[0];
    const int*   adj    = (const int*)d_in[1];
    const int*   mask   = (const int*)d_in[2];
    const float* a0     = (const float*)d_in[3];
    const float* a1     = (const float*)d_in[4];
    const float* a2     = (const float*)d_in[5];
    const float* a3     = (const float*)d_in[6];
    const float* W      = (const float*)d_in[7];
    const float* bias   = (const float*)d_in[8];
    float* out = (float*)d_out;

    const int B = in_sizes[0] / (NB * DIMH);   // 256

    const size_t hsN = (size_t)B * NB * 64;
    const size_t htN = (size_t)B * DIMH * KJ2;
    const size_t fullU32 = (size_t)WF_U32 + 2 * hsN + 2 * htN;   // layout unchanged (ht_lo slot unused)

    if (ws_size >= fullU32 * sizeof(unsigned)) {
        unsigned* wf    = (unsigned*)d_ws;
        unsigned* hs_hi = wf + WF_U32;
        unsigned* hs_lo = hs_hi + hsN;
        unsigned* ht_hi = hs_lo + hsN;
        conv_w<<<64, 64, 0, stream>>>(W, wf);
        conv_hs<<<(unsigned)(hsN / 256), 256, 0, stream>>>(hidden, hs_hi, hs_lo);
        conv_ht<<<B * 28, 256, 0, stream>>>(hidden, ht_hi);
        dim3 grid8(B * (NB / ROWS8));
        la_fused8<<<grid8, TPB8, 0, stream>>>(hidden, adj, mask, a0, a1, a2, a3,
                                              bias, wf, hs_hi, hs_lo, ht_hi, out);
    } else if (ws_size >= (size_t)WF_U32 * sizeof(unsigned)) {
        unsigned* wf = (unsigned*)d_ws;
        conv_w<<<64, 64, 0, stream>>>(W, wf);
        dim3 grid4(B * (NB / ROWS));
        la_fused<1><<<grid4, TPB, 0, stream>>>(hidden, adj, mask, a0, a1, a2, a3,
                                               W, bias, wf, out);
    } else {
        dim3 grid4(B * (NB / ROWS));
        la_fused<0><<<grid4, TPB, 0, stream>>>(hidden, adj, mask, a0, a1, a2, a3,
                                               W, bias, nullptr, out);
    }
}